// Round 20
// baseline (543.460 us; speedup 1.0000x reference)
//
#include <hip/hip_runtime.h>

// Problem sizes (fixed by reference setup_inputs)
#define B_  64
#define L_  1024
#define F_  900
#define E_  8
#define D_  768
#define SE_ 64
#define KP_ 928                      // K padded to 29*32
#define FD_ (F_*D_)                  // 691200
#define OUT_MAIN (64*1024*768)       // 50331648
#define GL_OFF   OUT_MAIN            // f32 index of guide_loss
#define SE_OFF   (OUT_MAIN + 1)      // f32 index of selemb[0][0]
#define EPSF 1e-9f
#define NT_  29                      // K tiles

// WORLD MODEL (final): d_out is f32; fout[0..OUT_MAIN)=final_out (B,L,D),
// fout[OUT_MAIN]=guide_loss, then selemb (B,SE). Standard input layouts.
// R17 370us; R18 417 (prep-heavy); R19 452 (gemm 193, prep 259 - worse).
// R20: NO prep pipeline. Dual-expert GEMM: A from X f32 (reg-staged cvt),
// B1/B2 from per-expert Wt bf16 (gload_lds), blend in f32 epilogue.

using f32x4  = __attribute__((ext_vector_type(4))) float;
using bf16   = __bf16;
using bf16x4 = __attribute__((ext_vector_type(4))) __bf16;
using bf16x8 = __attribute__((ext_vector_type(8))) __bf16;
using s16x8  = __attribute__((ext_vector_type(8))) short;

__device__ __forceinline__ f32x4 mfma_bf16(bf16x8 a, bf16x8 b, f32x4 c) {
  return __builtin_amdgcn_mfma_f32_16x16x32_bf16(
      __builtin_bit_cast(s16x8, a), __builtin_bit_cast(s16x8, b), c, 0, 0, 0);
}

__device__ __forceinline__ void gload16(const bf16* g, bf16* l) {
  __builtin_amdgcn_global_load_lds(
      (const __attribute__((address_space(1))) unsigned int*)g,
      (__attribute__((address_space(3))) unsigned int*)l, 16, 0, 0);
}

__device__ __forceinline__ const unsigned* pick_masks(const void* cA, const void* cB,
                                                      const float** logits) {
  const unsigned* a = (const unsigned*)cA;
  bool aIsMask = true;
#pragma unroll
  for (int i = 0; i < 512; i += 37) aIsMask &= (a[i] <= 1u);
  if (aIsMask) { *logits = (const float*)cB; return a; }
  *logits = (const float*)cA; return (const unsigned*)cB;
}

struct Gate { int e1, e2; float p1, p2; };

__device__ __forceinline__ Gate gate_for(const float* __restrict__ logits,
                                         const unsigned* __restrict__ masks, int b) {
  float lg[E_]; unsigned mk[E_];
#pragma unroll
  for (int e = 0; e < E_; ++e) { lg[e] = logits[b*E_+e]; mk[e] = masks[b*E_+e]; }
  float mx = lg[0];
#pragma unroll
  for (int e = 1; e < E_; ++e) mx = fmaxf(mx, lg[e]);
  float ex[E_], s = 0.f;
#pragma unroll
  for (int e = 0; e < E_; ++e) { ex[e] = expf(lg[e]-mx); s += ex[e]; }
  const float inv_s = 1.f / s;
  float p0[E_];
#pragma unroll
  for (int e = 0; e < E_; ++e) p0[e] = (mk[e] == 1u) ? ex[e]*inv_s : 0.f;
  int e1 = 0;
#pragma unroll
  for (int e = 1; e < E_; ++e) if (p0[e] > p0[e1]) e1 = e;   // ties -> low idx
  int e2 = (e1 == 0) ? 1 : 0;
#pragma unroll
  for (int e = 0; e < E_; ++e) if (e != e1 && p0[e] > p0[e2]) e2 = e;
  const float inv = 1.f / (p0[e1] + p0[e2] + EPSF);
  Gate g; g.e1 = e1; g.e2 = e2; g.p1 = p0[e1]*inv; g.p2 = p0[e2]*inv;
  return g;
}

// ---- gating: selection embedding + guide loss (f32 outputs) ----------------
__global__ void gating_kernel(const void* cA, const void* cB,
                              const float* __restrict__ selemb,
                              float* __restrict__ fout) {
  const float* logits; const unsigned* masks = pick_masks(cA, cB, &logits);
  const int b = threadIdx.x;   // 0..63
  float lg[E_]; unsigned mk[E_];
#pragma unroll
  for (int e = 0; e < E_; ++e) { lg[e] = logits[b*E_+e]; mk[e] = masks[b*E_+e]; }
  float mx = lg[0];
#pragma unroll
  for (int e = 1; e < E_; ++e) mx = fmaxf(mx, lg[e]);
  float ex[E_], s = 0.f;
#pragma unroll
  for (int e = 0; e < E_; ++e) { ex[e] = expf(lg[e]-mx); s += ex[e]; }
  const float inv_s = 1.f / s;
  float inact[E_]; float isum = 0.f, sact = 0.f;
#pragma unroll
  for (int e = 0; e < E_; ++e) {
    float raw = ex[e] * inv_s;
    if (mk[e] == 1u) { sact += raw; inact[e] = 0.f; }
    else             { inact[e] = raw; isum += raw; }
  }
  const float inv_i = 1.f / (isum + EPSF);
  for (int se = 0; se < SE_; ++se) {
    float a = 0.f;
#pragma unroll
    for (int e = 0; e < E_; ++e)
      a += inact[e] * inv_i * selemb[((size_t)b*E_ + e)*SE_ + se];
    fout[SE_OFF + b*SE_ + se] = a;
  }
#pragma unroll
  for (int off = 32; off > 0; off >>= 1) sact += __shfl_down(sact, off);
  if (b == 0) {
    float sm = sact / (float)B_;
    fout[GL_OFF] = (1.f - sm) * (1.f - sm);
  }
}

// ---- transw: W[E][F][D] f32 -> Wt[E][D][KP_] bf16 (0-pad K) [R17-proven] ---
__global__ void transw_kernel(const float* __restrict__ W, bf16* __restrict__ Wt) {
  __shared__ float tile[32][33];
  const int e  = blockIdx.z;
  const int d0 = blockIdx.x << 5;
  const int f0 = blockIdx.y << 5;
  const int c = threadIdx.x & 31, r = threadIdx.x >> 5;
#pragma unroll
  for (int p = 0; p < 4; ++p) {
    int f = f0 + p*8 + r;
    tile[p*8+r][c] = (f < F_) ? W[((size_t)e*F_ + f)*D_ + d0 + c] : 0.f;
  }
  __syncthreads();
#pragma unroll
  for (int p = 0; p < 4; ++p) {
    int d = d0 + p*8 + r;
    Wt[((size_t)e*D_ + d)*KP_ + f0 + c] = (bf16)tile[c][p*8+r];
  }
}

// ---- dual-expert GEMM: out = p1*(X@W[e1]) + p2*(X@W[e2]) -------------------
// A: X f32 reg-staged -> cvt -> swizzled ds_write (dbuf)
// B1/B2: Wt bf16 via gload_lds, pre-swizzled source (dbuf)
// counted-vmcnt pipeline, raw barriers, XCD-aware block map
__global__ __launch_bounds__(256) void gemm_fast(
    const float* __restrict__ X, const bf16* __restrict__ Wt,
    const float* __restrict__ bias,
    const void* cA, const void* cB,
    float* __restrict__ fout) {
  __shared__ bf16 As [2][128*32];
  __shared__ bf16 B1s[2][128*32];
  __shared__ bf16 B2s[2][128*32];

  const int id  = blockIdx.x;
  const int xcd = id & 7, q = id >> 3;        // 3072 = 8 * 384
  const int b   = xcd + ((q / 48) << 3);      // 48 consecutive q = one batch
  const int j   = q % 48;
  const int bn  = j % 6, bm = j / 6;

  const float* logits; const unsigned* masks = pick_masks(cA, cB, &logits);
  const Gate g = gate_for(logits, masks, b);

  const float* Xb = X  + ((size_t)b*L_ + (size_t)bm*128) * F_;
  const bf16*  W1 = Wt + ((size_t)g.e1*D_ + (size_t)bn*128) * KP_;
  const bf16*  W2 = Wt + ((size_t)g.e2*D_ + (size_t)bn*128) * KP_;

  const int t = threadIdx.x, lane = t & 63, w = t >> 6;

  // B staging via gload16: LDS slot s = w*128 + i*64 + lane (16B each);
  // row = s>>2, dest slot sl = lane&3; source k-slot = sl ^ (row&3) (rule #21)
  const int sw   = ((lane & 3) ^ ((lane >> 2) & 3)) << 3;
  const int row0 = (w << 5) + (lane >> 2);
  const int row1 = row0 + 16;
  const int dst0 = (w << 7) << 3;
  const int dst1 = dst0 + (64 << 3);

  auto STAGE_B = [&](int buf, int kt) {
    const int k0 = kt << 5;
    gload16(W1 + (size_t)row0*KP_ + k0 + sw, &B1s[buf][dst0]);
    gload16(W1 + (size_t)row1*KP_ + k0 + sw, &B1s[buf][dst1]);
    gload16(W2 + (size_t)row0*KP_ + k0 + sw, &B2s[buf][dst0]);
    gload16(W2 + (size_t)row1*KP_ + k0 + sw, &B2s[buf][dst1]);
  };

  // A staging: thread owns row arow, half akh (16 f32). XOR-swizzled write.
  const int arow = t >> 1, akh = t & 1;
  const float* Asrc = Xb + (size_t)arow*F_ + akh*16;
  const int aw0 = arow*32 + ((((akh<<1)|0) ^ (arow & 3)) << 3);
  const int aw1 = arow*32 + ((((akh<<1)|1) ^ (arow & 3)) << 3);

  f32x4 ax[4];
  auto LOAD_A = [&](int kt) {
    const int k0 = kt << 5;
    if (kt < NT_ - 1) {
#pragma unroll
      for (int i = 0; i < 4; ++i) ax[i] = *(const f32x4*)(Asrc + k0 + i*4);
    } else {  // tail tile k0=896: guard k >= 900
#pragma unroll
      for (int i = 0; i < 4; ++i)
#pragma unroll
        for (int jj = 0; jj < 4; ++jj) {
          int k = k0 + akh*16 + i*4 + jj;
          ax[i][jj] = (k < F_) ? Xb[(size_t)arow*F_ + k] : 0.f;
        }
    }
  };
  auto WRITE_A = [&](int buf) {
    bf16x8 v0, v1;
#pragma unroll
    for (int jj = 0; jj < 4; ++jj) {
      v0[jj] = (bf16)ax[0][jj]; v0[4+jj] = (bf16)ax[1][jj];
      v1[jj] = (bf16)ax[2][jj]; v1[4+jj] = (bf16)ax[3][jj];
    }
    *(bf16x8*)&As[buf][aw0] = v0;
    *(bf16x8*)&As[buf][aw1] = v1;
  };

  const int wr = (w >> 1) << 6, wc = (w & 1) << 6;   // 64x64 wave tile
  const int fr = lane & 15, fks = lane >> 4;
  const int rq = (lane >> 4) << 2;

  int aoff[4], boff[4];
#pragma unroll
  for (int m = 0; m < 4; ++m) {
    int rA = wr + m*16 + fr;
    aoff[m] = rA*32 + ((fks ^ (rA & 3)) << 3);
    int rB = wc + m*16 + fr;
    boff[m] = rB*32 + ((fks ^ (rB & 3)) << 3);
  }

  f32x4 acc1[4][4], acc2[4][4];
#pragma unroll
  for (int m = 0; m < 4; ++m)
#pragma unroll
    for (int n = 0; n < 4; ++n) {
      acc1[m][n] = (f32x4){0.f,0.f,0.f,0.f};
      acc2[m][n] = (f32x4){0.f,0.f,0.f,0.f};
    }

  LOAD_A(0);            // 4 reg loads in flight
  STAGE_B(0, 0);        // +4 lds loads
  int cur = 0;
#pragma unroll 1
  for (int kt = 0; kt < NT_; ++kt) {
    // A(kt) regs ready (compiler inserts precise vmcnt for ax use)
    WRITE_A(cur);
    if (kt + 1 < NT_) {
      LOAD_A(kt + 1);                              // +4 reg loads
      STAGE_B(cur ^ 1, kt + 1);                    // +4 lds loads
      asm volatile("s_waitcnt vmcnt(8)" ::: "memory");   // B(kt) landed
    } else {
      asm volatile("s_waitcnt vmcnt(0)" ::: "memory");
    }
    asm volatile("s_waitcnt lgkmcnt(0)" ::: "memory");   // ds_writes done
    __builtin_amdgcn_sched_barrier(0);
    __builtin_amdgcn_s_barrier();                  // tile kt fully in LDS
    __builtin_amdgcn_sched_barrier(0);
    bf16x8 af[4], b1f[4], b2f[4];
#pragma unroll
    for (int m = 0; m < 4; ++m) af[m]  = *(const bf16x8*)&As [cur][aoff[m]];
#pragma unroll
    for (int n = 0; n < 4; ++n) b1f[n] = *(const bf16x8*)&B1s[cur][boff[n]];
#pragma unroll
    for (int n = 0; n < 4; ++n) b2f[n] = *(const bf16x8*)&B2s[cur][boff[n]];
#pragma unroll
    for (int m = 0; m < 4; ++m)
#pragma unroll
      for (int n = 0; n < 4; ++n) {
        acc1[m][n] = mfma_bf16(af[m], b1f[n], acc1[m][n]);
        acc2[m][n] = mfma_bf16(af[m], b2f[n], acc2[m][n]);
      }
    __builtin_amdgcn_sched_barrier(0);
    __builtin_amdgcn_s_barrier();                  // reads done -> buf free
    cur ^= 1;
  }

  // epilogue (f32): blend experts; C/D layout col=lane&15, row=(lane>>4)*4+i
  const float* b1 = bias + g.e1*D_;
  const float* b2 = bias + g.e2*D_;
#pragma unroll
  for (int n = 0; n < 4; ++n) {
    int gc = bn*128 + wc + n*16 + fr;
    float bs = g.p1*b1[gc] + g.p2*b2[gc];
#pragma unroll
    for (int m = 0; m < 4; ++m) {
      size_t base = ((size_t)b*L_ + (size_t)(bm*128 + wr + m*16 + rq)) * D_ + gc;
#pragma unroll
      for (int i = 0; i < 4; ++i)
        fout[base + (size_t)i*D_] = g.p1*acc1[m][n][i] + g.p2*acc2[m][n][i] + bs;
    }
  }
}

// ---- last-resort f32 fallback (ws too small) -------------------------------
__global__ __launch_bounds__(128) void fallback_kernel(
    const float* __restrict__ X, const float* __restrict__ W,
    const float* __restrict__ bias,
    const void* cA, const void* cB,
    float* __restrict__ fout) {
  __shared__ float xs[16 * F_];
  const int t  = threadIdx.x;
  const int d  = blockIdx.x * 128 + t;
  const int l0 = blockIdx.y * 16;
  const int b  = blockIdx.z;
  const float* logits; const unsigned* masks = pick_masks(cA, cB, &logits);
  const Gate g = gate_for(logits, masks, b);
  const float* xrow = X + ((size_t)b*L_ + l0) * F_;
  for (int i = t; i < 16 * F_; i += 128) xs[i] = xrow[i];
  __syncthreads();
  const float* w1 = W + (size_t)g.e1*FD_ + d;
  const float* w2 = W + (size_t)g.e2*FD_ + d;
  float acc[16];
#pragma unroll
  for (int j = 0; j < 16; ++j) acc[j] = 0.f;
  for (int k = 0; k < F_; k += 4) {
    float wb[4];
#pragma unroll
    for (int q = 0; q < 4; ++q)
      wb[q] = g.p1 * w1[(size_t)(k+q)*D_] + g.p2 * w2[(size_t)(k+q)*D_];
#pragma unroll
    for (int j = 0; j < 16; ++j) {
      f32x4 xv = *(const f32x4*)&xs[j*F_ + k];
#pragma unroll
      for (int q = 0; q < 4; ++q) acc[j] += xv[q] * wb[q];
    }
  }
  const float bs = g.p1*bias[g.e1*D_+d] + g.p2*bias[g.e2*D_+d];
#pragma unroll
  for (int j = 0; j < 16; ++j)
    fout[((size_t)b*L_ + (size_t)(l0 + j)) * D_ + d] = acc[j] + bs;
}

extern "C" void kernel_launch(void* const* d_in, const int* in_sizes, int n_in,
                              void* d_out, int out_size, void* d_ws, size_t ws_size,
                              hipStream_t stream) {
  const float *X = nullptr, *selemb = nullptr, *W = nullptr, *bias = nullptr;
  const void *cA = nullptr, *cB = nullptr;
  for (int i = 0; i < n_in; ++i) {
    switch (in_sizes[i]) {
      case 58982400: X      = (const float*)d_in[i]; break;
      case 32768:    selemb = (const float*)d_in[i]; break;
      case 5529600:  W      = (const float*)d_in[i]; break;
      case 6144:     bias   = (const float*)d_in[i]; break;
      case 512:      if (!cA) cA = d_in[i]; else cB = d_in[i]; break;
      default: break;
    }
  }
  if (!X)      X      = (const float*)d_in[0];
  if (!cA)     cA     = d_in[1];
  if (!cB)     cB     = d_in[2];
  if (!selemb) selemb = (const float*)d_in[3];
  if (!W)      W      = (const float*)d_in[4];
  if (!bias)   bias   = (const float*)d_in[5];
  float* fout = (float*)d_out;

  const size_t need = (size_t)E_*D_*KP_*2;   // Wt, 11.4 MB

  gating_kernel<<<1, 64, 0, stream>>>(cA, cB, selemb, fout);
  if (ws_size >= need) {
    bf16* Wt = (bf16*)d_ws;
    transw_kernel<<<dim3(24, 29, 8), 256, 0, stream>>>(W, Wt);
    gemm_fast<<<3072, 256, 0, stream>>>(X, Wt, bias, cA, cB, fout);
  } else {
    fallback_kernel<<<dim3(6, 64, 64), 128, 0, stream>>>(X, W, bias, cA, cB, fout);
  }
}

// Round 22
// 395.298 us; speedup vs baseline: 1.3748x; 1.3748x over previous
//
#include <hip/hip_runtime.h>

// Problem sizes (fixed by reference setup_inputs)
#define B_  64
#define L_  1024
#define F_  900
#define E_  8
#define D_  768
#define SE_ 64
#define KP_ 928                      // K padded to 29*32
#define FD_ (F_*D_)                  // 691200
#define OUT_MAIN (64*1024*768)       // 50331648
#define GL_OFF   OUT_MAIN            // f32 index of guide_loss
#define SE_OFF   (OUT_MAIN + 1)      // f32 index of selemb[0][0]
#define EPSF 1e-9f
#define NT_  29                      // K tiles

// WORLD MODEL (final): d_out is f32; fout[0..OUT_MAIN)=final_out (B,L,D),
// fout[OUT_MAIN]=guide_loss, then selemb (B,SE). Standard input layouts.
// R17 370 PASS. R18 417 PASS (gemm 250, preps 167). R19 452 PASS (gemm 193
// replay-proven, preps 259). R20 543 PASS. R21 FAIL post-timing replay race
// (reg-staged A + vmcnt(6) under-drain suspect).
// R22: R19's replay-proven gemm + fast preps (xconv v3 2048 blocks, wmix v3).

using f32x4  = __attribute__((ext_vector_type(4))) float;
using bf16   = __bf16;
using bf16x4 = __attribute__((ext_vector_type(4))) __bf16;
using bf16x8 = __attribute__((ext_vector_type(8))) __bf16;
using s16x8  = __attribute__((ext_vector_type(8))) short;

__device__ __forceinline__ f32x4 mfma_bf16(bf16x8 a, bf16x8 b, f32x4 c) {
  return __builtin_amdgcn_mfma_f32_16x16x32_bf16(
      __builtin_bit_cast(s16x8, a), __builtin_bit_cast(s16x8, b), c, 0, 0, 0);
}

__device__ __forceinline__ void gload16(const bf16* g, bf16* l) {
  __builtin_amdgcn_global_load_lds(
      (const __attribute__((address_space(1))) unsigned int*)g,
      (__attribute__((address_space(3))) unsigned int*)l, 16, 0, 0);
}

__device__ __forceinline__ const unsigned* pick_masks(const void* cA, const void* cB,
                                                      const float** logits) {
  const unsigned* a = (const unsigned*)cA;
  bool aIsMask = true;
#pragma unroll
  for (int i = 0; i < 512; i += 37) aIsMask &= (a[i] <= 1u);
  if (aIsMask) { *logits = (const float*)cB; return a; }
  *logits = (const float*)cA; return (const unsigned*)cB;
}

struct Gate { int e1, e2; float p1, p2; };

__device__ __forceinline__ Gate gate_for(const float* __restrict__ logits,
                                         const unsigned* __restrict__ masks, int b) {
  float lg[E_]; unsigned mk[E_];
#pragma unroll
  for (int e = 0; e < E_; ++e) { lg[e] = logits[b*E_+e]; mk[e] = masks[b*E_+e]; }
  float mx = lg[0];
#pragma unroll
  for (int e = 1; e < E_; ++e) mx = fmaxf(mx, lg[e]);
  float ex[E_], s = 0.f;
#pragma unroll
  for (int e = 0; e < E_; ++e) { ex[e] = expf(lg[e]-mx); s += ex[e]; }
  const float inv_s = 1.f / s;
  float p0[E_];
#pragma unroll
  for (int e = 0; e < E_; ++e) p0[e] = (mk[e] == 1u) ? ex[e]*inv_s : 0.f;
  int e1 = 0;
#pragma unroll
  for (int e = 1; e < E_; ++e) if (p0[e] > p0[e1]) e1 = e;   // ties -> low idx
  int e2 = (e1 == 0) ? 1 : 0;
#pragma unroll
  for (int e = 0; e < E_; ++e) if (e != e1 && p0[e] > p0[e2]) e2 = e;
  const float inv = 1.f / (p0[e1] + p0[e2] + EPSF);
  Gate g; g.e1 = e1; g.e2 = e2; g.p1 = p0[e1]*inv; g.p2 = p0[e2]*inv;
  return g;
}

// ---- gating: selection embedding + guide loss (f32 outputs) ----------------
__global__ void gating_kernel(const void* cA, const void* cB,
                              const float* __restrict__ selemb,
                              float* __restrict__ fout) {
  const float* logits; const unsigned* masks = pick_masks(cA, cB, &logits);
  const int b = threadIdx.x;   // 0..63
  float lg[E_]; unsigned mk[E_];
#pragma unroll
  for (int e = 0; e < E_; ++e) { lg[e] = logits[b*E_+e]; mk[e] = masks[b*E_+e]; }
  float mx = lg[0];
#pragma unroll
  for (int e = 1; e < E_; ++e) mx = fmaxf(mx, lg[e]);
  float ex[E_], s = 0.f;
#pragma unroll
  for (int e = 0; e < E_; ++e) { ex[e] = expf(lg[e]-mx); s += ex[e]; }
  const float inv_s = 1.f / s;
  float inact[E_]; float isum = 0.f, sact = 0.f;
#pragma unroll
  for (int e = 0; e < E_; ++e) {
    float raw = ex[e] * inv_s;
    if (mk[e] == 1u) { sact += raw; inact[e] = 0.f; }
    else             { inact[e] = raw; isum += raw; }
  }
  const float inv_i = 1.f / (isum + EPSF);
  for (int se = 0; se < SE_; ++se) {
    float a = 0.f;
#pragma unroll
    for (int e = 0; e < E_; ++e)
      a += inact[e] * inv_i * selemb[((size_t)b*E_ + e)*SE_ + se];
    fout[SE_OFF + b*SE_ + se] = a;
  }
#pragma unroll
  for (int off = 32; off > 0; off >>= 1) sact += __shfl_down(sact, off);
  if (b == 0) {
    float sm = sact / (float)B_;
    fout[GL_OFF] = (1.f - sm) * (1.f - sm);
  }
}

// ---- xconv v3: X f32 -> Xbf bf16 [row][KP_]; 2048 blocks, 29 exact iters ---
// Slot space: 65536 rows x 232 bf16x4-slots = 15,204,352 = 29 * 524288.
__global__ __launch_bounds__(256) void xconv_kernel(const float* __restrict__ X,
                                                    bf16* __restrict__ Xbf) {
  int idx = blockIdx.x * 256 + threadIdx.x;      // stride 524288, 29 iters
#pragma unroll 1
  for (int it = 0; it < 29; ++it, idx += 524288) {
    const int row = idx / 232;                   // const-div -> magic mul
    const int s   = idx - row * 232;
    bf16x4 o;
    if (s < 225) {
      f32x4 v = *(const f32x4*)(X + (size_t)row*F_ + s*4);
#pragma unroll
      for (int j = 0; j < 4; ++j) o[j] = (bf16)v[j];
    } else {
      o = (bf16x4){(bf16)0.f,(bf16)0.f,(bf16)0.f,(bf16)0.f};
    }
    *(bf16x4*)(Xbf + (size_t)row*KP_ + s*4) = o;
  }
}

// ---- wmix v3: Wmix[b][d][KP_] bf16 = p1*W[e1][f][d] + p2*W[e2][f][d] -------
// 768 blocks = 64 batches x 12 d-chunks(64); lane = d (coalesced 256B reads).
__global__ __launch_bounds__(256) void wmix_kernel(const float* __restrict__ W,
                                                   const void* cA, const void* cB,
                                                   bf16* __restrict__ Wmix) {
  const int b  = blockIdx.x / 12;
  const int dc = blockIdx.x - b*12;
  const float* logits; const unsigned* masks = pick_masks(cA, cB, &logits);
  const Gate g = gate_for(logits, masks, b);
  const int lane = threadIdx.x & 63, w = threadIdx.x >> 6;
  const int d = (dc << 6) + lane;
  const float* W1 = W + (size_t)g.e1*FD_ + d;
  const float* W2 = W + (size_t)g.e2*FD_ + d;
  bf16* dst = Wmix + ((size_t)b*D_ + d)*KP_;
#pragma unroll 1
  for (int i = 0; i < 29; ++i) {
    const int f0 = (w + (i << 2)) << 3;   // octets w, w+4, ..., 29 each
    float v[8];
#pragma unroll
    for (int jj = 0; jj < 8; ++jj) {
      int f = f0 + jj;
      v[jj] = (f < F_) ? g.p1*W1[(size_t)f*D_] + g.p2*W2[(size_t)f*D_] : 0.f;
    }
    bf16x8 pk;
#pragma unroll
    for (int jj = 0; jj < 8; ++jj) pk[jj] = (bf16)v[jj];
    *(bf16x8*)(dst + f0) = pk;
  }
}

// ---- gemm_fast: R19 VERBATIM (replay-proven) -------------------------------
// A from Xbf, B from Wmix, both via gload16; counted vmcnt(4); XOR swizzle;
// XCD-aware block map.
__global__ __launch_bounds__(256) void gemm_fast(
    const bf16* __restrict__ Xbf, const bf16* __restrict__ Wmix,
    const float* __restrict__ bias,
    const void* cA, const void* cB,
    float* __restrict__ fout) {
  __shared__ bf16 As[2][128*32];
  __shared__ bf16 Bs[2][128*32];

  const int id  = blockIdx.x;
  const int xcd = id & 7, q = id >> 3;        // 3072 = 8 * 384
  const int b   = xcd + ((q / 48) << 3);      // 48 consecutive q = one batch
  const int j   = q % 48;
  const int bn  = j % 6, bm = j / 6;

  const float* logits; const unsigned* masks = pick_masks(cA, cB, &logits);
  const Gate g = gate_for(logits, masks, b);

  const bf16* Ab = Xbf  + ((size_t)b*L_ + (size_t)bm*128) * KP_;
  const bf16* Bb = Wmix + ((size_t)b*D_ + (size_t)bn*128) * KP_;

  const int t = threadIdx.x, lane = t & 63, w = t >> 6;
  const int sw   = ((lane & 3) ^ ((lane >> 2) & 3)) << 3;   // pre-swizzle
  const int row0 = (w << 5) + (lane >> 2);
  const int row1 = row0 + 16;
  const int dst0 = (w << 7) << 3;
  const int dst1 = dst0 + (64 << 3);

  auto STAGE = [&](int buf, int kt) {
    const int k0 = kt << 5;
    gload16(Ab + (size_t)row0*KP_ + k0 + sw, &As[buf][dst0]);
    gload16(Ab + (size_t)row1*KP_ + k0 + sw, &As[buf][dst1]);
    gload16(Bb + (size_t)row0*KP_ + k0 + sw, &Bs[buf][dst0]);
    gload16(Bb + (size_t)row1*KP_ + k0 + sw, &Bs[buf][dst1]);
  };

  const int wr = (w >> 1) << 6, wc = (w & 1) << 6;   // 64x64 wave tile
  const int fr = lane & 15, fks = lane >> 4;
  const int rq = (lane >> 4) << 2;

  int aoff[4], boff[4];
#pragma unroll
  for (int m = 0; m < 4; ++m) {
    int rA = wr + m*16 + fr;
    aoff[m] = rA*32 + ((fks ^ (rA & 3)) << 3);
    int rB = wc + m*16 + fr;
    boff[m] = rB*32 + ((fks ^ (rB & 3)) << 3);
  }

  f32x4 acc[4][4];
#pragma unroll
  for (int m = 0; m < 4; ++m)
#pragma unroll
    for (int n = 0; n < 4; ++n) acc[m][n] = (f32x4){0.f,0.f,0.f,0.f};

  STAGE(0, 0);
  int cur = 0;
#pragma unroll 1
  for (int kt = 0; kt < NT_; ++kt) {
    if (kt + 1 < NT_) {
      STAGE(cur ^ 1, kt + 1);                  // new 4 loads in flight
      asm volatile("s_waitcnt vmcnt(4)" ::: "memory");   // old 4 landed
    } else {
      asm volatile("s_waitcnt vmcnt(0)" ::: "memory");
    }
    __builtin_amdgcn_sched_barrier(0);
    __builtin_amdgcn_s_barrier();              // all waves' loads landed
    __builtin_amdgcn_sched_barrier(0);
    bf16x8 af[4], bfv[4];
#pragma unroll
    for (int m = 0; m < 4; ++m) af[m]  = *(const bf16x8*)&As[cur][aoff[m]];
#pragma unroll
    for (int n = 0; n < 4; ++n) bfv[n] = *(const bf16x8*)&Bs[cur][boff[n]];
#pragma unroll
    for (int m = 0; m < 4; ++m)
#pragma unroll
      for (int n = 0; n < 4; ++n)
        acc[m][n] = mfma_bf16(af[m], bfv[n], acc[m][n]);
    __builtin_amdgcn_sched_barrier(0);
    __builtin_amdgcn_s_barrier();              // reads done -> buf reusable
    cur ^= 1;
  }

  // epilogue (f32): C/D layout col=lane&15, row=(lane>>4)*4+i (R17-verified)
  const float* b1 = bias + g.e1*D_;
  const float* b2 = bias + g.e2*D_;
#pragma unroll
  for (int n = 0; n < 4; ++n) {
    int gc = bn*128 + wc + n*16 + fr;
    float bs = g.p1*b1[gc] + g.p2*b2[gc];
#pragma unroll
    for (int m = 0; m < 4; ++m) {
      size_t base = ((size_t)b*L_ + (size_t)(bm*128 + wr + m*16 + rq)) * D_ + gc;
#pragma unroll
      for (int i = 0; i < 4; ++i)
        fout[base + (size_t)i*D_] = acc[m][n][i] + bs;
    }
  }
}

// ======================= R17 mid path (ws >= 11.4MB) ========================
__global__ void transw_kernel(const float* __restrict__ W, bf16* __restrict__ Wt) {
  __shared__ float tile[32][33];
  const int e  = blockIdx.z;
  const int d0 = blockIdx.x << 5;
  const int f0 = blockIdx.y << 5;
  const int c = threadIdx.x & 31, r = threadIdx.x >> 5;
#pragma unroll
  for (int p = 0; p < 4; ++p) {
    int f = f0 + p*8 + r;
    tile[p*8+r][c] = (f < F_) ? W[((size_t)e*F_ + f)*D_ + d0 + c] : 0.f;
  }
  __syncthreads();
#pragma unroll
  for (int p = 0; p < 4; ++p) {
    int d = d0 + p*8 + r;
    Wt[((size_t)e*D_ + d)*KP_ + f0 + c] = (bf16)tile[c][p*8+r];
  }
}

__global__ __launch_bounds__(256) void gemm_kernel(
    const float* __restrict__ X, const bf16* __restrict__ Wt,
    const float* __restrict__ bias,
    const void* cA, const void* cB,
    float* __restrict__ fout) {
  __shared__ bf16 As[128][40];
  __shared__ bf16 Bs[128][40];
  const int bn = blockIdx.x, bm = blockIdx.y, b = blockIdx.z;
  const float* logits; const unsigned* masks = pick_masks(cA, cB, &logits);
  const Gate g = gate_for(logits, masks, b);
  const float* Xb = X + ((size_t)b*L_ + (size_t)bm*128) * F_;
  const bf16* W1 = Wt + ((size_t)g.e1*D_ + (size_t)bn*128) * KP_;
  const bf16* W2 = Wt + ((size_t)g.e2*D_ + (size_t)bn*128) * KP_;
  const int t  = threadIdx.x;
  const int ar = t >> 3, ac = (t & 7) << 2;
  const int br = t >> 2, bc = (t & 3) << 3;
  const int lane = t & 63, wave = t >> 6;
  const int wr = (wave >> 1) << 6, wc = (wave & 1) << 6;
  const int fr = lane & 15, fk = (lane >> 4) << 3;
  const int rq = (lane >> 4) << 2;
  f32x4 acc[4][4];
#pragma unroll
  for (int m = 0; m < 4; ++m)
#pragma unroll
    for (int n = 0; n < 4; ++n) acc[m][n] = (f32x4){0.f,0.f,0.f,0.f};
  f32x4 ax[4]; bf16x8 wv1[2], wv2[2];
  auto LOAD = [&](int k0) {
    if (k0 <= F_ - 32) {
#pragma unroll
      for (int p = 0; p < 4; ++p)
        ax[p] = *(const f32x4*)(Xb + (size_t)(p*32 + ar)*F_ + k0 + ac);
    } else {
#pragma unroll
      for (int p = 0; p < 4; ++p)
#pragma unroll
        for (int jj = 0; jj < 4; ++jj) {
          int k = k0 + ac + jj;
          ax[p][jj] = (k < F_) ? Xb[(size_t)(p*32 + ar)*F_ + k] : 0.f;
        }
    }
#pragma unroll
    for (int p = 0; p < 2; ++p) {
      wv1[p] = *(const bf16x8*)(W1 + (size_t)(p*64 + br)*KP_ + k0 + bc);
      wv2[p] = *(const bf16x8*)(W2 + (size_t)(p*64 + br)*KP_ + k0 + bc);
    }
  };
  auto STAGE = [&]() {
#pragma unroll
    for (int p = 0; p < 4; ++p) {
      bf16x4 v;
#pragma unroll
      for (int jj = 0; jj < 4; ++jj) v[jj] = (bf16)ax[p][jj];
      *(bf16x4*)&As[p*32 + ar][ac] = v;
    }
#pragma unroll
    for (int p = 0; p < 2; ++p) {
      bf16x8 v;
#pragma unroll
      for (int jj = 0; jj < 8; ++jj)
        v[jj] = (bf16)(g.p1 * (float)wv1[p][jj] + g.p2 * (float)wv2[p][jj]);
      *(bf16x8*)&Bs[p*64 + br][bc] = v;
    }
  };
  LOAD(0);
  for (int kt = 0; kt < NT_; ++kt) {
    STAGE();
    __syncthreads();
    if (kt + 1 < NT_) LOAD((kt + 1) << 5);
    bf16x8 af[4], bfv[4];
#pragma unroll
    for (int m = 0; m < 4; ++m) af[m]  = *(const bf16x8*)&As[wr + m*16 + fr][fk];
#pragma unroll
    for (int n = 0; n < 4; ++n) bfv[n] = *(const bf16x8*)&Bs[wc + n*16 + fr][fk];
#pragma unroll
    for (int m = 0; m < 4; ++m)
#pragma unroll
      for (int n = 0; n < 4; ++n)
        acc[m][n] = mfma_bf16(af[m], bfv[n], acc[m][n]);
    __syncthreads();
  }
  const float* b1 = bias + g.e1*D_;
  const float* b2 = bias + g.e2*D_;
#pragma unroll
  for (int n = 0; n < 4; ++n) {
    int gc = bn*128 + wc + n*16 + fr;
    float bs = g.p1*b1[gc] + g.p2*b2[gc];
#pragma unroll
    for (int m = 0; m < 4; ++m) {
      size_t base = ((size_t)b*L_ + (size_t)(bm*128 + wr + m*16 + rq)) * D_ + gc;
#pragma unroll
      for (int i = 0; i < 4; ++i)
        fout[base + (size_t)i*D_] = acc[m][n][i] + bs;
    }
  }
}

// ---- last-resort f32 fallback (ws too small) -------------------------------
__global__ __launch_bounds__(128) void fallback_kernel(
    const float* __restrict__ X, const float* __restrict__ W,
    const float* __restrict__ bias,
    const void* cA, const void* cB,
    float* __restrict__ fout) {
  __shared__ float xs[16 * F_];
  const int t  = threadIdx.x;
  const int d  = blockIdx.x * 128 + t;
  const int l0 = blockIdx.y * 16;
  const int b  = blockIdx.z;
  const float* logits; const unsigned* masks = pick_masks(cA, cB, &logits);
  const Gate g = gate_for(logits, masks, b);
  const float* xrow = X + ((size_t)b*L_ + l0) * F_;
  for (int i = t; i < 16 * F_; i += 128) xs[i] = xrow[i];
  __syncthreads();
  const float* w1 = W + (size_t)g.e1*FD_ + d;
  const float* w2 = W + (size_t)g.e2*FD_ + d;
  float acc[16];
#pragma unroll
  for (int jj = 0; jj < 16; ++jj) acc[jj] = 0.f;
  for (int k = 0; k < F_; k += 4) {
    float wb[4];
#pragma unroll
    for (int qq = 0; qq < 4; ++qq)
      wb[qq] = g.p1 * w1[(size_t)(k+qq)*D_] + g.p2 * w2[(size_t)(k+qq)*D_];
#pragma unroll
    for (int jj = 0; jj < 16; ++jj) {
      f32x4 xv = *(const f32x4*)&xs[jj*F_ + k];
#pragma unroll
      for (int qq = 0; qq < 4; ++qq) acc[jj] += xv[qq] * wb[qq];
    }
  }
  const float bs = g.p1*bias[g.e1*D_+d] + g.p2*bias[g.e2*D_+d];
#pragma unroll
  for (int jj = 0; jj < 16; ++jj)
    fout[((size_t)b*L_ + (size_t)(l0 + jj)) * D_ + d] = acc[jj] + bs;
}

extern "C" void kernel_launch(void* const* d_in, const int* in_sizes, int n_in,
                              void* d_out, int out_size, void* d_ws, size_t ws_size,
                              hipStream_t stream) {
  const float *X = nullptr, *selemb = nullptr, *W = nullptr, *bias = nullptr;
  const void *cA = nullptr, *cB = nullptr;
  for (int i = 0; i < n_in; ++i) {
    switch (in_sizes[i]) {
      case 58982400: X      = (const float*)d_in[i]; break;
      case 32768:    selemb = (const float*)d_in[i]; break;
      case 5529600:  W      = (const float*)d_in[i]; break;
      case 6144:     bias   = (const float*)d_in[i]; break;
      case 512:      if (!cA) cA = d_in[i]; else cB = d_in[i]; break;
      default: break;
    }
  }
  if (!X)      X      = (const float*)d_in[0];
  if (!cA)     cA     = d_in[1];
  if (!cB)     cB     = d_in[2];
  if (!selemb) selemb = (const float*)d_in[3];
  if (!W)      W      = (const float*)d_in[4];
  if (!bias)   bias   = (const float*)d_in[5];
  float* fout = (float*)d_out;

  const size_t xbf_bytes  = (size_t)B_*L_*KP_*2;         // 121,634,816
  const size_t wmix_bytes = (size_t)B_*D_*KP_*2;         //  91,226,112
  const size_t need_fast  = xbf_bytes + wmix_bytes;      // ~203 MB
  const size_t need_mid   = (size_t)E_*D_*KP_*2;         // ~11.4 MB

  gating_kernel<<<1, 64, 0, stream>>>(cA, cB, selemb, fout);

  if (ws_size >= need_fast) {
    bf16* Xbf  = (bf16*)d_ws;
    bf16* Wmix = (bf16*)((char*)d_ws + xbf_bytes);
    xconv_kernel<<<2048, 256, 0, stream>>>(X, Xbf);
    wmix_kernel<<<768, 256, 0, stream>>>(W, cA, cB, Wmix);
    gemm_fast<<<3072, 256, 0, stream>>>(Xbf, Wmix, bias, cA, cB, fout);
  } else if (ws_size >= need_mid) {
    bf16* Wt = (bf16*)d_ws;
    transw_kernel<<<dim3(24, 29, 8), 256, 0, stream>>>(W, Wt);
    gemm_kernel<<<dim3(6, 8, 64), 256, 0, stream>>>(X, Wt, bias, cA, cB, fout);
  } else {
    fallback_kernel<<<dim3(6, 64, 64), 128, 0, stream>>>(X, W, bias, cA, cB, fout);
  }
}

// Round 23
// 375.152 us; speedup vs baseline: 1.4486x; 1.0537x over previous
//
#include <hip/hip_runtime.h>

// Problem sizes (fixed by reference setup_inputs)
#define B_  64
#define L_  1024
#define F_  900
#define E_  8
#define D_  768
#define SE_ 64
#define KP_ 928                      // K padded to 29*32
#define FD_ (F_*D_)                  // 691200
#define OUT_MAIN (64*1024*768)       // 50331648
#define GL_OFF   OUT_MAIN            // f32 index of guide_loss
#define SE_OFF   (OUT_MAIN + 1)      // f32 index of selemb[0][0]
#define EPSF 1e-9f
#define NT_  29                      // K tiles

// WORLD MODEL (final): d_out is f32; fout[0..OUT_MAIN)=final_out (B,L,D),
// fout[OUT_MAIN]=guide_loss, then selemb (B,SE). Standard input layouts.
// R17 370 PASS. R19 gemm 193 replay-proven. R21 FAIL replay (reg-staged A).
// R22 395 PASS: gemm 195 (MfmaUtil 19.6, Occ 31.7, latency-bound), preps ~160.
// R23: gemm v3 = 3-deep LDS pipeline, vmcnt(8) exact counting (loads get 2
// iters to land); preps fused into one kernel (xconv || wmix || gating).

using f32x4  = __attribute__((ext_vector_type(4))) float;
using bf16   = __bf16;
using bf16x4 = __attribute__((ext_vector_type(4))) __bf16;
using bf16x8 = __attribute__((ext_vector_type(8))) __bf16;
using s16x8  = __attribute__((ext_vector_type(8))) short;

__device__ __forceinline__ f32x4 mfma_bf16(bf16x8 a, bf16x8 b, f32x4 c) {
  return __builtin_amdgcn_mfma_f32_16x16x32_bf16(
      __builtin_bit_cast(s16x8, a), __builtin_bit_cast(s16x8, b), c, 0, 0, 0);
}

__device__ __forceinline__ void gload16(const bf16* g, bf16* l) {
  __builtin_amdgcn_global_load_lds(
      (const __attribute__((address_space(1))) unsigned int*)g,
      (__attribute__((address_space(3))) unsigned int*)l, 16, 0, 0);
}

__device__ __forceinline__ const unsigned* pick_masks(const void* cA, const void* cB,
                                                      const float** logits) {
  const unsigned* a = (const unsigned*)cA;
  bool aIsMask = true;
#pragma unroll
  for (int i = 0; i < 512; i += 37) aIsMask &= (a[i] <= 1u);
  if (aIsMask) { *logits = (const float*)cB; return a; }
  *logits = (const float*)cA; return (const unsigned*)cB;
}

struct Gate { int e1, e2; float p1, p2; };

__device__ __forceinline__ Gate gate_for(const float* __restrict__ logits,
                                         const unsigned* __restrict__ masks, int b) {
  float lg[E_]; unsigned mk[E_];
#pragma unroll
  for (int e = 0; e < E_; ++e) { lg[e] = logits[b*E_+e]; mk[e] = masks[b*E_+e]; }
  float mx = lg[0];
#pragma unroll
  for (int e = 1; e < E_; ++e) mx = fmaxf(mx, lg[e]);
  float ex[E_], s = 0.f;
#pragma unroll
  for (int e = 0; e < E_; ++e) { ex[e] = expf(lg[e]-mx); s += ex[e]; }
  const float inv_s = 1.f / s;
  float p0[E_];
#pragma unroll
  for (int e = 0; e < E_; ++e) p0[e] = (mk[e] == 1u) ? ex[e]*inv_s : 0.f;
  int e1 = 0;
#pragma unroll
  for (int e = 1; e < E_; ++e) if (p0[e] > p0[e1]) e1 = e;   // ties -> low idx
  int e2 = (e1 == 0) ? 1 : 0;
#pragma unroll
  for (int e = 0; e < E_; ++e) if (e != e1 && p0[e] > p0[e2]) e2 = e;
  const float inv = 1.f / (p0[e1] + p0[e2] + EPSF);
  Gate g; g.e1 = e1; g.e2 = e2; g.p1 = p0[e1]*inv; g.p2 = p0[e2]*inv;
  return g;
}

// ---- gating body (device fn): selection embedding + guide loss -------------
__device__ __forceinline__ void gating_body(const void* cA, const void* cB,
                                            const float* __restrict__ selemb,
                                            float* __restrict__ fout, int b) {
  const float* logits; const unsigned* masks = pick_masks(cA, cB, &logits);
  float lg[E_]; unsigned mk[E_];
#pragma unroll
  for (int e = 0; e < E_; ++e) { lg[e] = logits[b*E_+e]; mk[e] = masks[b*E_+e]; }
  float mx = lg[0];
#pragma unroll
  for (int e = 1; e < E_; ++e) mx = fmaxf(mx, lg[e]);
  float ex[E_], s = 0.f;
#pragma unroll
  for (int e = 0; e < E_; ++e) { ex[e] = expf(lg[e]-mx); s += ex[e]; }
  const float inv_s = 1.f / s;
  float inact[E_]; float isum = 0.f, sact = 0.f;
#pragma unroll
  for (int e = 0; e < E_; ++e) {
    float raw = ex[e] * inv_s;
    if (mk[e] == 1u) { sact += raw; inact[e] = 0.f; }
    else             { inact[e] = raw; isum += raw; }
  }
  const float inv_i = 1.f / (isum + EPSF);
  for (int se = 0; se < SE_; ++se) {
    float a = 0.f;
#pragma unroll
    for (int e = 0; e < E_; ++e)
      a += inact[e] * inv_i * selemb[((size_t)b*E_ + e)*SE_ + se];
    fout[SE_OFF + b*SE_ + se] = a;
  }
#pragma unroll
  for (int off = 32; off > 0; off >>= 1) sact += __shfl_down(sact, off);
  if (b == 0) {
    float sm = sact / (float)B_;
    fout[GL_OFF] = (1.f - sm) * (1.f - sm);
  }
}

__global__ void gating_kernel(const void* cA, const void* cB,
                              const float* __restrict__ selemb,
                              float* __restrict__ fout) {
  gating_body(cA, cB, selemb, fout, threadIdx.x);
}

// ---- fused prep: blocks 0..2047 xconv | 2048..2815 wmix | 2816 gating ------
__global__ __launch_bounds__(256) void prep_kernel(
    const float* __restrict__ X, const float* __restrict__ W,
    const void* cA, const void* cB, const float* __restrict__ selemb,
    bf16* __restrict__ Xbf, bf16* __restrict__ Wmix,
    float* __restrict__ fout) {
  const int blk = blockIdx.x;
  if (blk < 2048) {
    // xconv: 65536 rows x 232 bf16x4-slots = 15,204,352 = 29 * 524288
    int idx = blk * 256 + threadIdx.x;
#pragma unroll 1
    for (int it = 0; it < 29; ++it, idx += 524288) {
      const int row = idx / 232;
      const int s   = idx - row * 232;
      bf16x4 o;
      if (s < 225) {
        f32x4 v = *(const f32x4*)(X + (size_t)row*F_ + s*4);
#pragma unroll
        for (int j = 0; j < 4; ++j) o[j] = (bf16)v[j];
      } else {
        o = (bf16x4){(bf16)0.f,(bf16)0.f,(bf16)0.f,(bf16)0.f};
      }
      *(bf16x4*)(Xbf + (size_t)row*KP_ + s*4) = o;
    }
  } else if (blk < 2816) {
    // wmix: 768 blocks = 64 batches x 12 d-chunks(64); lane = d
    const int wb = blk - 2048;
    const int b  = wb / 12;
    const int dc = wb - b*12;
    const float* logits; const unsigned* masks = pick_masks(cA, cB, &logits);
    const Gate g = gate_for(logits, masks, b);
    const int lane = threadIdx.x & 63, w = threadIdx.x >> 6;
    const int d = (dc << 6) + lane;
    const float* W1 = W + (size_t)g.e1*FD_ + d;
    const float* W2 = W + (size_t)g.e2*FD_ + d;
    bf16* dst = Wmix + ((size_t)b*D_ + d)*KP_;
#pragma unroll 1
    for (int i = 0; i < 29; ++i) {
      const int f0 = (w + (i << 2)) << 3;   // octets w, w+4, ..., 29 each
      float v[8];
#pragma unroll
      for (int jj = 0; jj < 8; ++jj) {
        int f = f0 + jj;
        v[jj] = (f < F_) ? g.p1*W1[(size_t)f*D_] + g.p2*W2[(size_t)f*D_] : 0.f;
      }
      bf16x8 pk;
#pragma unroll
      for (int jj = 0; jj < 8; ++jj) pk[jj] = (bf16)v[jj];
      *(bf16x8*)(dst + f0) = pk;
    }
  } else {
    if (threadIdx.x < 64) gating_body(cA, cB, selemb, fout, threadIdx.x);
  }
}

// ---- gemm v3: 3-deep LDS pipeline, exact vmcnt counting --------------------
// A from Xbf, B from Wmix via gload16 (4 loads/iter, deterministic);
// stage kt+2, wait vmcnt(8): loads get 2 iterations to land.
__global__ __launch_bounds__(256) void gemm_fast(
    const bf16* __restrict__ Xbf, const bf16* __restrict__ Wmix,
    const float* __restrict__ bias,
    const void* cA, const void* cB,
    float* __restrict__ fout) {
  __shared__ bf16 As[3][128*32];
  __shared__ bf16 Bs[3][128*32];

  const int id  = blockIdx.x;
  const int xcd = id & 7, q = id >> 3;        // 3072 = 8 * 384
  const int b   = xcd + ((q / 48) << 3);      // 48 consecutive q = one batch
  const int j   = q % 48;
  const int bn  = j % 6, bm = j / 6;

  const float* logits; const unsigned* masks = pick_masks(cA, cB, &logits);
  const Gate g = gate_for(logits, masks, b);

  const bf16* Ab = Xbf  + ((size_t)b*L_ + (size_t)bm*128) * KP_;
  const bf16* Bb = Wmix + ((size_t)b*D_ + (size_t)bn*128) * KP_;

  const int t = threadIdx.x, lane = t & 63, w = t >> 6;
  const int sw   = ((lane & 3) ^ ((lane >> 2) & 3)) << 3;   // pre-swizzle
  const int row0 = (w << 5) + (lane >> 2);
  const int row1 = row0 + 16;
  const int dst0 = (w << 7) << 3;
  const int dst1 = dst0 + (64 << 3);

  auto STAGE = [&](int buf, int kt) {
    const int k0 = kt << 5;
    gload16(Ab + (size_t)row0*KP_ + k0 + sw, &As[buf][dst0]);
    gload16(Ab + (size_t)row1*KP_ + k0 + sw, &As[buf][dst1]);
    gload16(Bb + (size_t)row0*KP_ + k0 + sw, &Bs[buf][dst0]);
    gload16(Bb + (size_t)row1*KP_ + k0 + sw, &Bs[buf][dst1]);
  };

  const int wr = (w >> 1) << 6, wc = (w & 1) << 6;   // 64x64 wave tile
  const int fr = lane & 15, fks = lane >> 4;
  const int rq = (lane >> 4) << 2;

  int aoff[4], boff[4];
#pragma unroll
  for (int m = 0; m < 4; ++m) {
    int rA = wr + m*16 + fr;
    aoff[m] = rA*32 + ((fks ^ (rA & 3)) << 3);
    int rB = wc + m*16 + fr;
    boff[m] = rB*32 + ((fks ^ (rB & 3)) << 3);
  }

  // preload bias blend (loop-invariant; before the pipeline so in-loop VMEM
  // is exactly the 4 gload16/iter - keeps vmcnt counting exact)
  const float* b1 = bias + g.e1*D_;
  const float* b2 = bias + g.e2*D_;
  float bsv[4];
#pragma unroll
  for (int n = 0; n < 4; ++n) {
    int gc = bn*128 + wc + n*16 + fr;
    bsv[n] = g.p1*b1[gc] + g.p2*b2[gc];
  }

  f32x4 acc[4][4];
#pragma unroll
  for (int m = 0; m < 4; ++m)
#pragma unroll
    for (int n = 0; n < 4; ++n) acc[m][n] = (f32x4){0.f,0.f,0.f,0.f};

  STAGE(0, 0);
  STAGE(1, 1);
  int cur = 0;                         // buffer holding tile kt
#pragma unroll 1
  for (int kt = 0; kt < NT_; ++kt) {
    if (kt + 2 < NT_) {
      const int sb = (cur + 2 >= 3) ? cur - 1 : cur + 2;
      STAGE(sb, kt + 2);               // 12 outstanding after issue
      asm volatile("s_waitcnt vmcnt(8)" ::: "memory");   // tile kt landed
    } else if (kt + 2 == NT_) {
      asm volatile("s_waitcnt vmcnt(4)" ::: "memory");   // tile kt landed
    } else {
      asm volatile("s_waitcnt vmcnt(0)" ::: "memory");
    }
    __builtin_amdgcn_sched_barrier(0);
    __builtin_amdgcn_s_barrier();      // all waves' tile-kt loads landed
    __builtin_amdgcn_sched_barrier(0);
    bf16x8 af[4], bfv[4];
#pragma unroll
    for (int m = 0; m < 4; ++m) af[m]  = *(const bf16x8*)&As[cur][aoff[m]];
#pragma unroll
    for (int n = 0; n < 4; ++n) bfv[n] = *(const bf16x8*)&Bs[cur][boff[n]];
#pragma unroll
    for (int m = 0; m < 4; ++m)
#pragma unroll
      for (int n = 0; n < 4; ++n)
        acc[m][n] = mfma_bf16(af[m], bfv[n], acc[m][n]);
    __builtin_amdgcn_sched_barrier(0);
    __builtin_amdgcn_s_barrier();      // reads of buf[cur] done (WAR guard)
    cur = (cur + 1 == 3) ? 0 : cur + 1;
  }

  // epilogue (f32): C/D layout col=lane&15, row=(lane>>4)*4+i (R17-verified)
#pragma unroll
  for (int n = 0; n < 4; ++n) {
    int gc = bn*128 + wc + n*16 + fr;
#pragma unroll
    for (int m = 0; m < 4; ++m) {
      size_t base = ((size_t)b*L_ + (size_t)(bm*128 + wr + m*16 + rq)) * D_ + gc;
#pragma unroll
      for (int i = 0; i < 4; ++i)
        fout[base + (size_t)i*D_] = acc[m][n][i] + bsv[n];
    }
  }
}

// ======================= R17 mid path (ws >= 11.4MB) ========================
__global__ void transw_kernel(const float* __restrict__ W, bf16* __restrict__ Wt) {
  __shared__ float tile[32][33];
  const int e  = blockIdx.z;
  const int d0 = blockIdx.x << 5;
  const int f0 = blockIdx.y << 5;
  const int c = threadIdx.x & 31, r = threadIdx.x >> 5;
#pragma unroll
  for (int p = 0; p < 4; ++p) {
    int f = f0 + p*8 + r;
    tile[p*8+r][c] = (f < F_) ? W[((size_t)e*F_ + f)*D_ + d0 + c] : 0.f;
  }
  __syncthreads();
#pragma unroll
  for (int p = 0; p < 4; ++p) {
    int d = d0 + p*8 + r;
    Wt[((size_t)e*D_ + d)*KP_ + f0 + c] = (bf16)tile[c][p*8+r];
  }
}

__global__ __launch_bounds__(256) void gemm_kernel(
    const float* __restrict__ X, const bf16* __restrict__ Wt,
    const float* __restrict__ bias,
    const void* cA, const void* cB,
    float* __restrict__ fout) {
  __shared__ bf16 As[128][40];
  __shared__ bf16 Bs[128][40];
  const int bn = blockIdx.x, bm = blockIdx.y, b = blockIdx.z;
  const float* logits; const unsigned* masks = pick_masks(cA, cB, &logits);
  const Gate g = gate_for(logits, masks, b);
  const float* Xb = X + ((size_t)b*L_ + (size_t)bm*128) * F_;
  const bf16* W1 = Wt + ((size_t)g.e1*D_ + (size_t)bn*128) * KP_;
  const bf16* W2 = Wt + ((size_t)g.e2*D_ + (size_t)bn*128) * KP_;
  const int t  = threadIdx.x;
  const int ar = t >> 3, ac = (t & 7) << 2;
  const int br = t >> 2, bc = (t & 3) << 3;
  const int lane = t & 63, wave = t >> 6;
  const int wr = (wave >> 1) << 6, wc = (wave & 1) << 6;
  const int fr = lane & 15, fk = (lane >> 4) << 3;
  const int rq = (lane >> 4) << 2;
  f32x4 acc[4][4];
#pragma unroll
  for (int m = 0; m < 4; ++m)
#pragma unroll
    for (int n = 0; n < 4; ++n) acc[m][n] = (f32x4){0.f,0.f,0.f,0.f};
  f32x4 ax[4]; bf16x8 wv1[2], wv2[2];
  auto LOAD = [&](int k0) {
    if (k0 <= F_ - 32) {
#pragma unroll
      for (int p = 0; p < 4; ++p)
        ax[p] = *(const f32x4*)(Xb + (size_t)(p*32 + ar)*F_ + k0 + ac);
    } else {
#pragma unroll
      for (int p = 0; p < 4; ++p)
#pragma unroll
        for (int jj = 0; jj < 4; ++jj) {
          int k = k0 + ac + jj;
          ax[p][jj] = (k < F_) ? Xb[(size_t)(p*32 + ar)*F_ + k] : 0.f;
        }
    }
#pragma unroll
    for (int p = 0; p < 2; ++p) {
      wv1[p] = *(const bf16x8*)(W1 + (size_t)(p*64 + br)*KP_ + k0 + bc);
      wv2[p] = *(const bf16x8*)(W2 + (size_t)(p*64 + br)*KP_ + k0 + bc);
    }
  };
  auto STAGE = [&]() {
#pragma unroll
    for (int p = 0; p < 4; ++p) {
      bf16x4 v;
#pragma unroll
      for (int jj = 0; jj < 4; ++jj) v[jj] = (bf16)ax[p][jj];
      *(bf16x4*)&As[p*32 + ar][ac] = v;
    }
#pragma unroll
    for (int p = 0; p < 2; ++p) {
      bf16x8 v;
#pragma unroll
      for (int jj = 0; jj < 8; ++jj)
        v[jj] = (bf16)(g.p1 * (float)wv1[p][jj] + g.p2 * (float)wv2[p][jj]);
      *(bf16x8*)&Bs[p*64 + br][bc] = v;
    }
  };
  LOAD(0);
  for (int kt = 0; kt < NT_; ++kt) {
    STAGE();
    __syncthreads();
    if (kt + 1 < NT_) LOAD((kt + 1) << 5);
    bf16x8 af[4], bfv[4];
#pragma unroll
    for (int m = 0; m < 4; ++m) af[m]  = *(const bf16x8*)&As[wr + m*16 + fr][fk];
#pragma unroll
    for (int n = 0; n < 4; ++n) bfv[n] = *(const bf16x8*)&Bs[wc + n*16 + fr][fk];
#pragma unroll
    for (int m = 0; m < 4; ++m)
#pragma unroll
      for (int n = 0; n < 4; ++n)
        acc[m][n] = mfma_bf16(af[m], bfv[n], acc[m][n]);
    __syncthreads();
  }
  const float* b1 = bias + g.e1*D_;
  const float* b2 = bias + g.e2*D_;
#pragma unroll
  for (int n = 0; n < 4; ++n) {
    int gc = bn*128 + wc + n*16 + fr;
    float bs = g.p1*b1[gc] + g.p2*b2[gc];
#pragma unroll
    for (int m = 0; m < 4; ++m) {
      size_t base = ((size_t)b*L_ + (size_t)(bm*128 + wr + m*16 + rq)) * D_ + gc;
#pragma unroll
      for (int i = 0; i < 4; ++i)
        fout[base + (size_t)i*D_] = acc[m][n][i] + bs;
    }
  }
}

// ---- last-resort f32 fallback (ws too small) -------------------------------
__global__ __launch_bounds__(128) void fallback_kernel(
    const float* __restrict__ X, const float* __restrict__ W,
    const float* __restrict__ bias,
    const void* cA, const void* cB,
    float* __restrict__ fout) {
  __shared__ float xs[16 * F_];
  const int t  = threadIdx.x;
  const int d  = blockIdx.x * 128 + t;
  const int l0 = blockIdx.y * 16;
  const int b  = blockIdx.z;
  const float* logits; const unsigned* masks = pick_masks(cA, cB, &logits);
  const Gate g = gate_for(logits, masks, b);
  const float* xrow = X + ((size_t)b*L_ + l0) * F_;
  for (int i = t; i < 16 * F_; i += 128) xs[i] = xrow[i];
  __syncthreads();
  const float* w1 = W + (size_t)g.e1*FD_ + d;
  const float* w2 = W + (size_t)g.e2*FD_ + d;
  float acc[16];
#pragma unroll
  for (int jj = 0; jj < 16; ++jj) acc[jj] = 0.f;
  for (int k = 0; k < F_; k += 4) {
    float wb[4];
#pragma unroll
    for (int qq = 0; qq < 4; ++qq)
      wb[qq] = g.p1 * w1[(size_t)(k+qq)*D_] + g.p2 * w2[(size_t)(k+qq)*D_];
#pragma unroll
    for (int jj = 0; jj < 16; ++jj) {
      f32x4 xv = *(const f32x4*)&xs[jj*F_ + k];
#pragma unroll
      for (int qq = 0; qq < 4; ++qq) acc[jj] += xv[qq] * wb[qq];
    }
  }
  const float bs = g.p1*bias[g.e1*D_+d] + g.p2*bias[g.e2*D_+d];
#pragma unroll
  for (int jj = 0; jj < 16; ++jj)
    fout[((size_t)b*L_ + (size_t)(l0 + jj)) * D_ + d] = acc[jj] + bs;
}

extern "C" void kernel_launch(void* const* d_in, const int* in_sizes, int n_in,
                              void* d_out, int out_size, void* d_ws, size_t ws_size,
                              hipStream_t stream) {
  const float *X = nullptr, *selemb = nullptr, *W = nullptr, *bias = nullptr;
  const void *cA = nullptr, *cB = nullptr;
  for (int i = 0; i < n_in; ++i) {
    switch (in_sizes[i]) {
      case 58982400: X      = (const float*)d_in[i]; break;
      case 32768:    selemb = (const float*)d_in[i]; break;
      case 5529600:  W      = (const float*)d_in[i]; break;
      case 6144:     bias   = (const float*)d_in[i]; break;
      case 512:      if (!cA) cA = d_in[i]; else cB = d_in[i]; break;
      default: break;
    }
  }
  if (!X)      X      = (const float*)d_in[0];
  if (!cA)     cA     = d_in[1];
  if (!cB)     cB     = d_in[2];
  if (!selemb) selemb = (const float*)d_in[3];
  if (!W)      W      = (const float*)d_in[4];
  if (!bias)   bias   = (const float*)d_in[5];
  float* fout = (float*)d_out;

  const size_t xbf_bytes  = (size_t)B_*L_*KP_*2;         // 121,634,816
  const size_t wmix_bytes = (size_t)B_*D_*KP_*2;         //  91,226,112
  const size_t need_fast  = xbf_bytes + wmix_bytes;      // ~203 MB
  const size_t need_mid   = (size_t)E_*D_*KP_*2;         // ~11.4 MB

  if (ws_size >= need_fast) {
    bf16* Xbf  = (bf16*)d_ws;
    bf16* Wmix = (bf16*)((char*)d_ws + xbf_bytes);
    prep_kernel<<<2817, 256, 0, stream>>>(X, W, cA, cB, selemb, Xbf, Wmix, fout);
    gemm_fast<<<3072, 256, 0, stream>>>(Xbf, Wmix, bias, cA, cB, fout);
  } else if (ws_size >= need_mid) {
    bf16* Wt = (bf16*)d_ws;
    gating_kernel<<<1, 64, 0, stream>>>(cA, cB, selemb, fout);
    transw_kernel<<<dim3(24, 29, 8), 256, 0, stream>>>(W, Wt);
    gemm_kernel<<<dim3(6, 8, 64), 256, 0, stream>>>(X, Wt, bias, cA, cB, fout);
  } else {
    gating_kernel<<<1, 64, 0, stream>>>(cA, cB, selemb, fout);
    fallback_kernel<<<dim3(6, 64, 64), 128, 0, stream>>>(X, W, bias, cA, cB, fout);
  }
}

// Round 24
// 363.284 us; speedup vs baseline: 1.4960x; 1.0327x over previous
//
#include <hip/hip_runtime.h>

// Problem sizes (fixed by reference setup_inputs)
#define B_  64
#define L_  1024
#define F_  900
#define E_  8
#define D_  768
#define SE_ 64
#define KP_ 928                      // K padded to 29*32
#define FD_ (F_*D_)                  // 691200
#define OUT_MAIN (64*1024*768)       // 50331648
#define GL_OFF   OUT_MAIN            // f32 index of guide_loss
#define SE_OFF   (OUT_MAIN + 1)      // f32 index of selemb[0][0]
#define EPSF 1e-9f
#define NT_  29                      // K tiles

// WORLD MODEL: d_out is f32; fout[0..OUT_MAIN)=final_out (B,L,D),
// fout[OUT_MAIN]=guide_loss, then selemb (B,SE). Standard input layouts.
// R22 395: gemm 195. R23 375: gemm<209 (3-deep pipe works), prep 213 is the
// bottleneck (1.7 TB/s vs 6.3 floor). R24: xconv v4 (4x MLP), wmix_t
// (LDS-transposed writes), separate kernels for rocprof attribution.

using f32x4  = __attribute__((ext_vector_type(4))) float;
using bf16   = __bf16;
using bf16x4 = __attribute__((ext_vector_type(4))) __bf16;
using bf16x8 = __attribute__((ext_vector_type(8))) __bf16;
using s16x8  = __attribute__((ext_vector_type(8))) short;

__device__ __forceinline__ f32x4 mfma_bf16(bf16x8 a, bf16x8 b, f32x4 c) {
  return __builtin_amdgcn_mfma_f32_16x16x32_bf16(
      __builtin_bit_cast(s16x8, a), __builtin_bit_cast(s16x8, b), c, 0, 0, 0);
}

__device__ __forceinline__ void gload16(const bf16* g, bf16* l) {
  __builtin_amdgcn_global_load_lds(
      (const __attribute__((address_space(1))) unsigned int*)g,
      (__attribute__((address_space(3))) unsigned int*)l, 16, 0, 0);
}

__device__ __forceinline__ const unsigned* pick_masks(const void* cA, const void* cB,
                                                      const float** logits) {
  const unsigned* a = (const unsigned*)cA;
  bool aIsMask = true;
#pragma unroll
  for (int i = 0; i < 512; i += 37) aIsMask &= (a[i] <= 1u);
  if (aIsMask) { *logits = (const float*)cB; return a; }
  *logits = (const float*)cA; return (const unsigned*)cB;
}

struct Gate { int e1, e2; float p1, p2; };

__device__ __forceinline__ Gate gate_for(const float* __restrict__ logits,
                                         const unsigned* __restrict__ masks, int b) {
  float lg[E_]; unsigned mk[E_];
#pragma unroll
  for (int e = 0; e < E_; ++e) { lg[e] = logits[b*E_+e]; mk[e] = masks[b*E_+e]; }
  float mx = lg[0];
#pragma unroll
  for (int e = 1; e < E_; ++e) mx = fmaxf(mx, lg[e]);
  float ex[E_], s = 0.f;
#pragma unroll
  for (int e = 0; e < E_; ++e) { ex[e] = expf(lg[e]-mx); s += ex[e]; }
  const float inv_s = 1.f / s;
  float p0[E_];
#pragma unroll
  for (int e = 0; e < E_; ++e) p0[e] = (mk[e] == 1u) ? ex[e]*inv_s : 0.f;
  int e1 = 0;
#pragma unroll
  for (int e = 1; e < E_; ++e) if (p0[e] > p0[e1]) e1 = e;   // ties -> low idx
  int e2 = (e1 == 0) ? 1 : 0;
#pragma unroll
  for (int e = 0; e < E_; ++e) if (e != e1 && p0[e] > p0[e2]) e2 = e;
  const float inv = 1.f / (p0[e1] + p0[e2] + EPSF);
  Gate g; g.e1 = e1; g.e2 = e2; g.p1 = p0[e1]*inv; g.p2 = p0[e2]*inv;
  return g;
}

// ---- gating: selection embedding + guide loss (f32 outputs) ----------------
__global__ void gating_kernel(const void* cA, const void* cB,
                              const float* __restrict__ selemb,
                              float* __restrict__ fout) {
  const float* logits; const unsigned* masks = pick_masks(cA, cB, &logits);
  const int b = threadIdx.x;   // 0..63
  float lg[E_]; unsigned mk[E_];
#pragma unroll
  for (int e = 0; e < E_; ++e) { lg[e] = logits[b*E_+e]; mk[e] = masks[b*E_+e]; }
  float mx = lg[0];
#pragma unroll
  for (int e = 1; e < E_; ++e) mx = fmaxf(mx, lg[e]);
  float ex[E_], s = 0.f;
#pragma unroll
  for (int e = 0; e < E_; ++e) { ex[e] = expf(lg[e]-mx); s += ex[e]; }
  const float inv_s = 1.f / s;
  float inact[E_]; float isum = 0.f, sact = 0.f;
#pragma unroll
  for (int e = 0; e < E_; ++e) {
    float raw = ex[e] * inv_s;
    if (mk[e] == 1u) { sact += raw; inact[e] = 0.f; }
    else             { inact[e] = raw; isum += raw; }
  }
  const float inv_i = 1.f / (isum + EPSF);
  for (int se = 0; se < SE_; ++se) {
    float a = 0.f;
#pragma unroll
    for (int e = 0; e < E_; ++e)
      a += inact[e] * inv_i * selemb[((size_t)b*E_ + e)*SE_ + se];
    fout[SE_OFF + b*SE_ + se] = a;
  }
#pragma unroll
  for (int off = 32; off > 0; off >>= 1) sact += __shfl_down(sact, off);
  if (b == 0) {
    float sm = sact / (float)B_;
    fout[GL_OFF] = (1.f - sm) * (1.f - sm);
  }
}

// ---- xconv v4: X f32 -> Xbf bf16 [row][KP_]; 4 loads in flight per iter ----
// Groups of 16 f32: 65536 rows x 58 groups = 3,801,088; 524288 threads x 8.
__global__ __launch_bounds__(256) void xconv_kernel(const float* __restrict__ X,
                                                    bf16* __restrict__ Xbf) {
  const int tid = blockIdx.x * 256 + threadIdx.x;   // 0..524287
#pragma unroll 1
  for (int it = 0; it < 8; ++it) {
    const int gidx = tid + it * 524288;
    if (gidx >= 65536 * 58) break;
    const int row = gidx / 58;
    const int gg  = gidx - row * 58;
    const int s0  = gg << 4;                        // f32 offset in padded row
    f32x4 a[4];
#pragma unroll
    for (int j = 0; j < 4; ++j) {                   // 4 independent loads
      const int f = s0 + (j << 2);
      if (f < F_) a[j] = *(const f32x4*)(X + (size_t)row*F_ + f);  // f<=896 full
      else        a[j] = (f32x4){0.f, 0.f, 0.f, 0.f};
    }
    bf16x8 o0, o1;
#pragma unroll
    for (int j = 0; j < 4; ++j) {
      o0[j]   = (bf16)a[0][j];  o0[4+j] = (bf16)a[1][j];
      o1[j]   = (bf16)a[2][j];  o1[4+j] = (bf16)a[3][j];
    }
    bf16* dst = Xbf + (size_t)row*KP_ + s0;
    *(bf16x8*)dst       = o0;
    *(bf16x8*)(dst + 8) = o1;
  }
}

// ---- wmix_t: Wmix[b][d][KP_] = blend, LDS-transposed (coalesced both ways) -
// 1536 blocks = 64 b x 24 d-chunks(32); loop 29 f-tiles(32).
__global__ __launch_bounds__(256) void wmix_kernel(const float* __restrict__ W,
                                                   const void* cA, const void* cB,
                                                   bf16* __restrict__ Wmix) {
  __shared__ float tile[32][33];
  const int blk = blockIdx.x;
  const int b   = blk / 24;
  const int dc  = blk - b*24;
  const int d0  = dc << 5;
  const float* logits; const unsigned* masks = pick_masks(cA, cB, &logits);
  const Gate g = gate_for(logits, masks, b);
  const float* W1 = W + (size_t)g.e1*FD_;
  const float* W2 = W + (size_t)g.e2*FD_;
  const int t = threadIdx.x;
  const int c = t & 31, r = t >> 5;        // load: c = d-lane, r = f-row base
  const int dl = t >> 3, qd = t & 7;       // store: dl = d-row, qd = f-quad
  bf16* dstb = Wmix + ((size_t)b*D_ + d0 + dl)*KP_;
#pragma unroll 1
  for (int ft = 0; ft < 29; ++ft) {
    const int f0 = ft << 5;
    float v[4];
#pragma unroll
    for (int p = 0; p < 4; ++p) {          // 8 independent loads (2 experts)
      const int f = f0 + (p << 3) + r;
      if (f < F_) {
        const size_t o = (size_t)f*D_ + d0 + c;
        v[p] = g.p1*W1[o] + g.p2*W2[o];
      } else v[p] = 0.f;
    }
    __syncthreads();                       // prev iteration's reads done
#pragma unroll
    for (int p = 0; p < 4; ++p) tile[(p << 3) + r][c] = v[p];
    __syncthreads();
    bf16x4 pk;
#pragma unroll
    for (int j = 0; j < 4; ++j) pk[j] = (bf16)tile[(qd << 2) + j][dl];
    *(bf16x4*)(dstb + f0 + (qd << 2)) = pk;   // 8B; 64B contig per d-row
  }
}

// ---- gemm v3 (R23 verbatim, replay-proven): 3-deep pipeline, vmcnt exact ---
__global__ __launch_bounds__(256) void gemm_fast(
    const bf16* __restrict__ Xbf, const bf16* __restrict__ Wmix,
    const float* __restrict__ bias,
    const void* cA, const void* cB,
    float* __restrict__ fout) {
  __shared__ bf16 As[3][128*32];
  __shared__ bf16 Bs[3][128*32];

  const int id  = blockIdx.x;
  const int xcd = id & 7, q = id >> 3;        // 3072 = 8 * 384
  const int b   = xcd + ((q / 48) << 3);      // 48 consecutive q = one batch
  const int j   = q % 48;
  const int bn  = j % 6, bm = j / 6;

  const float* logits; const unsigned* masks = pick_masks(cA, cB, &logits);
  const Gate g = gate_for(logits, masks, b);

  const bf16* Ab = Xbf  + ((size_t)b*L_ + (size_t)bm*128) * KP_;
  const bf16* Bb = Wmix + ((size_t)b*D_ + (size_t)bn*128) * KP_;

  const int t = threadIdx.x, lane = t & 63, w = t >> 6;
  const int sw   = ((lane & 3) ^ ((lane >> 2) & 3)) << 3;   // pre-swizzle
  const int row0 = (w << 5) + (lane >> 2);
  const int row1 = row0 + 16;
  const int dst0 = (w << 7) << 3;
  const int dst1 = dst0 + (64 << 3);

  auto STAGE = [&](int buf, int kt) {
    const int k0 = kt << 5;
    gload16(Ab + (size_t)row0*KP_ + k0 + sw, &As[buf][dst0]);
    gload16(Ab + (size_t)row1*KP_ + k0 + sw, &As[buf][dst1]);
    gload16(Bb + (size_t)row0*KP_ + k0 + sw, &Bs[buf][dst0]);
    gload16(Bb + (size_t)row1*KP_ + k0 + sw, &Bs[buf][dst1]);
  };

  const int wr = (w >> 1) << 6, wc = (w & 1) << 6;   // 64x64 wave tile
  const int fr = lane & 15, fks = lane >> 4;
  const int rq = (lane >> 4) << 2;

  int aoff[4], boff[4];
#pragma unroll
  for (int m = 0; m < 4; ++m) {
    int rA = wr + m*16 + fr;
    aoff[m] = rA*32 + ((fks ^ (rA & 3)) << 3);
    int rB = wc + m*16 + fr;
    boff[m] = rB*32 + ((fks ^ (rB & 3)) << 3);
  }

  // bias preload (keeps in-loop VMEM = exactly 4 gload16/iter)
  const float* b1 = bias + g.e1*D_;
  const float* b2 = bias + g.e2*D_;
  float bsv[4];
#pragma unroll
  for (int n = 0; n < 4; ++n) {
    int gc = bn*128 + wc + n*16 + fr;
    bsv[n] = g.p1*b1[gc] + g.p2*b2[gc];
  }

  f32x4 acc[4][4];
#pragma unroll
  for (int m = 0; m < 4; ++m)
#pragma unroll
    for (int n = 0; n < 4; ++n) acc[m][n] = (f32x4){0.f,0.f,0.f,0.f};

  STAGE(0, 0);
  STAGE(1, 1);
  int cur = 0;
#pragma unroll 1
  for (int kt = 0; kt < NT_; ++kt) {
    if (kt + 2 < NT_) {
      const int sb = (cur + 2 >= 3) ? cur - 1 : cur + 2;
      STAGE(sb, kt + 2);               // 12 outstanding after issue
      asm volatile("s_waitcnt vmcnt(8)" ::: "memory");   // tile kt landed
    } else if (kt + 2 == NT_) {
      asm volatile("s_waitcnt vmcnt(4)" ::: "memory");
    } else {
      asm volatile("s_waitcnt vmcnt(0)" ::: "memory");
    }
    __builtin_amdgcn_sched_barrier(0);
    __builtin_amdgcn_s_barrier();
    __builtin_amdgcn_sched_barrier(0);
    bf16x8 af[4], bfv[4];
#pragma unroll
    for (int m = 0; m < 4; ++m) af[m]  = *(const bf16x8*)&As[cur][aoff[m]];
#pragma unroll
    for (int n = 0; n < 4; ++n) bfv[n] = *(const bf16x8*)&Bs[cur][boff[n]];
#pragma unroll
    for (int m = 0; m < 4; ++m)
#pragma unroll
      for (int n = 0; n < 4; ++n)
        acc[m][n] = mfma_bf16(af[m], bfv[n], acc[m][n]);
    __builtin_amdgcn_sched_barrier(0);
    __builtin_amdgcn_s_barrier();      // WAR guard
    cur = (cur + 1 == 3) ? 0 : cur + 1;
  }

  // epilogue (f32): C/D layout col=lane&15, row=(lane>>4)*4+i (R17-verified)
#pragma unroll
  for (int n = 0; n < 4; ++n) {
    int gc = bn*128 + wc + n*16 + fr;
#pragma unroll
    for (int m = 0; m < 4; ++m) {
      size_t base = ((size_t)b*L_ + (size_t)(bm*128 + wr + m*16 + rq)) * D_ + gc;
#pragma unroll
      for (int i = 0; i < 4; ++i)
        fout[base + (size_t)i*D_] = acc[m][n][i] + bsv[n];
    }
  }
}

// ======================= R17 mid path (ws >= 11.4MB) ========================
__global__ void transw_kernel(const float* __restrict__ W, bf16* __restrict__ Wt) {
  __shared__ float tile[32][33];
  const int e  = blockIdx.z;
  const int d0 = blockIdx.x << 5;
  const int f0 = blockIdx.y << 5;
  const int c = threadIdx.x & 31, r = threadIdx.x >> 5;
#pragma unroll
  for (int p = 0; p < 4; ++p) {
    int f = f0 + p*8 + r;
    tile[p*8+r][c] = (f < F_) ? W[((size_t)e*F_ + f)*D_ + d0 + c] : 0.f;
  }
  __syncthreads();
#pragma unroll
  for (int p = 0; p < 4; ++p) {
    int d = d0 + p*8 + r;
    Wt[((size_t)e*D_ + d)*KP_ + f0 + c] = (bf16)tile[c][p*8+r];
  }
}

__global__ __launch_bounds__(256) void gemm_kernel(
    const float* __restrict__ X, const bf16* __restrict__ Wt,
    const float* __restrict__ bias,
    const void* cA, const void* cB,
    float* __restrict__ fout) {
  __shared__ bf16 As[128][40];
  __shared__ bf16 Bs[128][40];
  const int bn = blockIdx.x, bm = blockIdx.y, b = blockIdx.z;
  const float* logits; const unsigned* masks = pick_masks(cA, cB, &logits);
  const Gate g = gate_for(logits, masks, b);
  const float* Xb = X + ((size_t)b*L_ + (size_t)bm*128) * F_;
  const bf16* W1 = Wt + ((size_t)g.e1*D_ + (size_t)bn*128) * KP_;
  const bf16* W2 = Wt + ((size_t)g.e2*D_ + (size_t)bn*128) * KP_;
  const int t  = threadIdx.x;
  const int ar = t >> 3, ac = (t & 7) << 2;
  const int br = t >> 2, bc = (t & 3) << 3;
  const int lane = t & 63, wave = t >> 6;
  const int wr = (wave >> 1) << 6, wc = (wave & 1) << 6;
  const int fr = lane & 15, fk = (lane >> 4) << 3;
  const int rq = (lane >> 4) << 2;
  f32x4 acc[4][4];
#pragma unroll
  for (int m = 0; m < 4; ++m)
#pragma unroll
    for (int n = 0; n < 4; ++n) acc[m][n] = (f32x4){0.f,0.f,0.f,0.f};
  f32x4 ax[4]; bf16x8 wv1[2], wv2[2];
  auto LOAD = [&](int k0) {
    if (k0 <= F_ - 32) {
#pragma unroll
      for (int p = 0; p < 4; ++p)
        ax[p] = *(const f32x4*)(Xb + (size_t)(p*32 + ar)*F_ + k0 + ac);
    } else {
#pragma unroll
      for (int p = 0; p < 4; ++p)
#pragma unroll
        for (int jj = 0; jj < 4; ++jj) {
          int k = k0 + ac + jj;
          ax[p][jj] = (k < F_) ? Xb[(size_t)(p*32 + ar)*F_ + k] : 0.f;
        }
    }
#pragma unroll
    for (int p = 0; p < 2; ++p) {
      wv1[p] = *(const bf16x8*)(W1 + (size_t)(p*64 + br)*KP_ + k0 + bc);
      wv2[p] = *(const bf16x8*)(W2 + (size_t)(p*64 + br)*KP_ + k0 + bc);
    }
  };
  auto STAGE = [&]() {
#pragma unroll
    for (int p = 0; p < 4; ++p) {
      bf16x4 v;
#pragma unroll
      for (int jj = 0; jj < 4; ++jj) v[jj] = (bf16)ax[p][jj];
      *(bf16x4*)&As[p*32 + ar][ac] = v;
    }
#pragma unroll
    for (int p = 0; p < 2; ++p) {
      bf16x8 v;
#pragma unroll
      for (int jj = 0; jj < 8; ++jj)
        v[jj] = (bf16)(g.p1 * (float)wv1[p][jj] + g.p2 * (float)wv2[p][jj]);
      *(bf16x8*)&Bs[p*64 + br][bc] = v;
    }
  };
  LOAD(0);
  for (int kt = 0; kt < NT_; ++kt) {
    STAGE();
    __syncthreads();
    if (kt + 1 < NT_) LOAD((kt + 1) << 5);
    bf16x8 af[4], bfv[4];
#pragma unroll
    for (int m = 0; m < 4; ++m) af[m]  = *(const bf16x8*)&As[wr + m*16 + fr][fk];
#pragma unroll
    for (int n = 0; n < 4; ++n) bfv[n] = *(const bf16x8*)&Bs[wc + n*16 + fr][fk];
#pragma unroll
    for (int m = 0; m < 4; ++m)
#pragma unroll
      for (int n = 0; n < 4; ++n)
        acc[m][n] = mfma_bf16(af[m], bfv[n], acc[m][n]);
    __syncthreads();
  }
  const float* b1 = bias + g.e1*D_;
  const float* b2 = bias + g.e2*D_;
#pragma unroll
  for (int n = 0; n < 4; ++n) {
    int gc = bn*128 + wc + n*16 + fr;
    float bs = g.p1*b1[gc] + g.p2*b2[gc];
#pragma unroll
    for (int m = 0; m < 4; ++m) {
      size_t base = ((size_t)b*L_ + (size_t)(bm*128 + wr + m*16 + rq)) * D_ + gc;
#pragma unroll
      for (int i = 0; i < 4; ++i)
        fout[base + (size_t)i*D_] = acc[m][n][i] + bs;
    }
  }
}

// ---- last-resort f32 fallback (ws too small) -------------------------------
__global__ __launch_bounds__(128) void fallback_kernel(
    const float* __restrict__ X, const float* __restrict__ W,
    const float* __restrict__ bias,
    const void* cA, const void* cB,
    float* __restrict__ fout) {
  __shared__ float xs[16 * F_];
  const int t  = threadIdx.x;
  const int d  = blockIdx.x * 128 + t;
  const int l0 = blockIdx.y * 16;
  const int b  = blockIdx.z;
  const float* logits; const unsigned* masks = pick_masks(cA, cB, &logits);
  const Gate g = gate_for(logits, masks, b);
  const float* xrow = X + ((size_t)b*L_ + l0) * F_;
  for (int i = t; i < 16 * F_; i += 128) xs[i] = xrow[i];
  __syncthreads();
  const float* w1 = W + (size_t)g.e1*FD_ + d;
  const float* w2 = W + (size_t)g.e2*FD_ + d;
  float acc[16];
#pragma unroll
  for (int jj = 0; jj < 16; ++jj) acc[jj] = 0.f;
  for (int k = 0; k < F_; k += 4) {
    float wb[4];
#pragma unroll
    for (int qq = 0; qq < 4; ++qq)
      wb[qq] = g.p1 * w1[(size_t)(k+qq)*D_] + g.p2 * w2[(size_t)(k+qq)*D_];
#pragma unroll
    for (int jj = 0; jj < 16; ++jj) {
      f32x4 xv = *(const f32x4*)&xs[jj*F_ + k];
#pragma unroll
      for (int qq = 0; qq < 4; ++qq) acc[jj] += xv[qq] * wb[qq];
    }
  }
  const float bs = g.p1*bias[g.e1*D_+d] + g.p2*bias[g.e2*D_+d];
#pragma unroll
  for (int jj = 0; jj < 16; ++jj)
    fout[((size_t)b*L_ + (size_t)(l0 + jj)) * D_ + d] = acc[jj] + bs;
}

extern "C" void kernel_launch(void* const* d_in, const int* in_sizes, int n_in,
                              void* d_out, int out_size, void* d_ws, size_t ws_size,
                              hipStream_t stream) {
  const float *X = nullptr, *selemb = nullptr, *W = nullptr, *bias = nullptr;
  const void *cA = nullptr, *cB = nullptr;
  for (int i = 0; i < n_in; ++i) {
    switch (in_sizes[i]) {
      case 58982400: X      = (const float*)d_in[i]; break;
      case 32768:    selemb = (const float*)d_in[i]; break;
      case 5529600:  W      = (const float*)d_in[i]; break;
      case 6144:     bias   = (const float*)d_in[i]; break;
      case 512:      if (!cA) cA = d_in[i]; else cB = d_in[i]; break;
      default: break;
    }
  }
  if (!X)      X      = (const float*)d_in[0];
  if (!cA)     cA     = d_in[1];
  if (!cB)     cB     = d_in[2];
  if (!selemb) selemb = (const float*)d_in[3];
  if (!W)      W      = (const float*)d_in[4];
  if (!bias)   bias   = (const float*)d_in[5];
  float* fout = (float*)d_out;

  const size_t xbf_bytes  = (size_t)B_*L_*KP_*2;         // 121,634,816
  const size_t wmix_bytes = (size_t)B_*D_*KP_*2;         //  91,226,112
  const size_t need_fast  = xbf_bytes + wmix_bytes;      // ~203 MB
  const size_t need_mid   = (size_t)E_*D_*KP_*2;         // ~11.4 MB

  gating_kernel<<<1, 64, 0, stream>>>(cA, cB, selemb, fout);

  if (ws_size >= need_fast) {
    bf16* Xbf  = (bf16*)d_ws;
    bf16* Wmix = (bf16*)((char*)d_ws + xbf_bytes);
    xconv_kernel<<<2048, 256, 0, stream>>>(X, Xbf);
    wmix_kernel<<<1536, 256, 0, stream>>>(W, cA, cB, Wmix);
    gemm_fast<<<3072, 256, 0, stream>>>(Xbf, Wmix, bias, cA, cB, fout);
  } else if (ws_size >= need_mid) {
    bf16* Wt = (bf16*)d_ws;
    transw_kernel<<<dim3(24, 29, 8), 256, 0, stream>>>(W, Wt);
    gemm_kernel<<<dim3(6, 8, 64), 256, 0, stream>>>(X, Wt, bias, cA, cB, fout);
  } else {
    fallback_kernel<<<dim3(6, 64, 64), 128, 0, stream>>>(X, W, bias, cA, cB, fout);
  }
}

// Round 25
// 359.375 us; speedup vs baseline: 1.5122x; 1.0109x over previous
//
#include <hip/hip_runtime.h>

// Problem sizes (fixed by reference setup_inputs)
#define B_  64
#define L_  1024
#define F_  900
#define E_  8
#define D_  768
#define SE_ 64
#define KP_ 928                      // K padded to 29*32
#define FD_ (F_*D_)                  // 691200
#define OUT_MAIN (64*1024*768)       // 50331648
#define GL_OFF   OUT_MAIN            // f32 index of guide_loss
#define SE_OFF   (OUT_MAIN + 1)      // f32 index of selemb[0][0]
#define EPSF 1e-9f
#define NT_  29                      // K tiles

// WORLD MODEL: d_out is f32; fout[0..OUT_MAIN)=final_out (B,L,D),
// fout[OUT_MAIN]=guide_loss, then selemb (B,SE). Standard input layouts.
// R22 395: gemm 195 (2-deep). R24 363: gemm 195.5 (3-deep) => depth doesn't
// matter, gemm is barrier/LDS-throughput bound (~110us overlap floor).
// Prep ~164us over 3 launches. R25: fused prep (xconv v5 MLP=8 || wmix_t ||
// gating) in ONE launch; gemm untouched (replay-proven).

using f32x4  = __attribute__((ext_vector_type(4))) float;
using bf16   = __bf16;
using bf16x4 = __attribute__((ext_vector_type(4))) __bf16;
using bf16x8 = __attribute__((ext_vector_type(8))) __bf16;
using s16x8  = __attribute__((ext_vector_type(8))) short;

__device__ __forceinline__ f32x4 mfma_bf16(bf16x8 a, bf16x8 b, f32x4 c) {
  return __builtin_amdgcn_mfma_f32_16x16x32_bf16(
      __builtin_bit_cast(s16x8, a), __builtin_bit_cast(s16x8, b), c, 0, 0, 0);
}

__device__ __forceinline__ void gload16(const bf16* g, bf16* l) {
  __builtin_amdgcn_global_load_lds(
      (const __attribute__((address_space(1))) unsigned int*)g,
      (__attribute__((address_space(3))) unsigned int*)l, 16, 0, 0);
}

__device__ __forceinline__ const unsigned* pick_masks(const void* cA, const void* cB,
                                                      const float** logits) {
  const unsigned* a = (const unsigned*)cA;
  bool aIsMask = true;
#pragma unroll
  for (int i = 0; i < 512; i += 37) aIsMask &= (a[i] <= 1u);
  if (aIsMask) { *logits = (const float*)cB; return a; }
  *logits = (const float*)cA; return (const unsigned*)cB;
}

struct Gate { int e1, e2; float p1, p2; };

__device__ __forceinline__ Gate gate_for(const float* __restrict__ logits,
                                         const unsigned* __restrict__ masks, int b) {
  float lg[E_]; unsigned mk[E_];
#pragma unroll
  for (int e = 0; e < E_; ++e) { lg[e] = logits[b*E_+e]; mk[e] = masks[b*E_+e]; }
  float mx = lg[0];
#pragma unroll
  for (int e = 1; e < E_; ++e) mx = fmaxf(mx, lg[e]);
  float ex[E_], s = 0.f;
#pragma unroll
  for (int e = 0; e < E_; ++e) { ex[e] = expf(lg[e]-mx); s += ex[e]; }
  const float inv_s = 1.f / s;
  float p0[E_];
#pragma unroll
  for (int e = 0; e < E_; ++e) p0[e] = (mk[e] == 1u) ? ex[e]*inv_s : 0.f;
  int e1 = 0;
#pragma unroll
  for (int e = 1; e < E_; ++e) if (p0[e] > p0[e1]) e1 = e;   // ties -> low idx
  int e2 = (e1 == 0) ? 1 : 0;
#pragma unroll
  for (int e = 0; e < E_; ++e) if (e != e1 && p0[e] > p0[e2]) e2 = e;
  const float inv = 1.f / (p0[e1] + p0[e2] + EPSF);
  Gate g; g.e1 = e1; g.e2 = e2; g.p1 = p0[e1]*inv; g.p2 = p0[e2]*inv;
  return g;
}

// ---- gating body: selection embedding + guide loss (f32 outputs) -----------
__device__ __forceinline__ void gating_body(const void* cA, const void* cB,
                                            const float* __restrict__ selemb,
                                            float* __restrict__ fout, int b) {
  const float* logits; const unsigned* masks = pick_masks(cA, cB, &logits);
  float lg[E_]; unsigned mk[E_];
#pragma unroll
  for (int e = 0; e < E_; ++e) { lg[e] = logits[b*E_+e]; mk[e] = masks[b*E_+e]; }
  float mx = lg[0];
#pragma unroll
  for (int e = 1; e < E_; ++e) mx = fmaxf(mx, lg[e]);
  float ex[E_], s = 0.f;
#pragma unroll
  for (int e = 0; e < E_; ++e) { ex[e] = expf(lg[e]-mx); s += ex[e]; }
  const float inv_s = 1.f / s;
  float inact[E_]; float isum = 0.f, sact = 0.f;
#pragma unroll
  for (int e = 0; e < E_; ++e) {
    float raw = ex[e] * inv_s;
    if (mk[e] == 1u) { sact += raw; inact[e] = 0.f; }
    else             { inact[e] = raw; isum += raw; }
  }
  const float inv_i = 1.f / (isum + EPSF);
  for (int se = 0; se < SE_; ++se) {
    float a = 0.f;
#pragma unroll
    for (int e = 0; e < E_; ++e)
      a += inact[e] * inv_i * selemb[((size_t)b*E_ + e)*SE_ + se];
    fout[SE_OFF + b*SE_ + se] = a;
  }
#pragma unroll
  for (int off = 32; off > 0; off >>= 1) sact += __shfl_down(sact, off);
  if (b == 0) {
    float sm = sact / (float)B_;
    fout[GL_OFF] = (1.f - sm) * (1.f - sm);
  }
}

__global__ void gating_kernel(const void* cA, const void* cB,
                              const float* __restrict__ selemb,
                              float* __restrict__ fout) {
  gating_body(cA, cB, selemb, fout, threadIdx.x);
}

// ---- fused prep: 0..2047 xconv v5 | 2048..3583 wmix_t | 3584 gating --------
__global__ __launch_bounds__(256) void prep_kernel(
    const float* __restrict__ X, const float* __restrict__ W,
    const void* cA, const void* cB, const float* __restrict__ selemb,
    bf16* __restrict__ Xbf, bf16* __restrict__ Wmix,
    float* __restrict__ fout) {
  const int blk = blockIdx.x;
  if (blk < 2048) {
    // xconv v5: groups of 32 f32 (8 independent loads in flight).
    // 65536 rows x 29 groups = 1,900,544 tasks; 524288 threads x 4 iters.
    const int tid = blk * 256 + threadIdx.x;
#pragma unroll 1
    for (int it = 0; it < 4; ++it) {
      const int gidx = tid + it * 524288;
      if (gidx >= 65536 * 29) break;
      const int row = gidx / 29;
      const int gg  = gidx - row * 29;
      const int s0  = gg << 5;                      // f32 offset (0..896)
      f32x4 a[8];
#pragma unroll
      for (int j = 0; j < 8; ++j) {                 // 8 independent loads
        const int f = s0 + (j << 2);
        if (f < F_) a[j] = *(const f32x4*)(X + (size_t)row*F_ + f);
        else        a[j] = (f32x4){0.f, 0.f, 0.f, 0.f};
      }
      bf16x8 o[4];
#pragma unroll
      for (int p = 0; p < 4; ++p)
#pragma unroll
        for (int j = 0; j < 4; ++j) {
          o[p][j]   = (bf16)a[2*p][j];
          o[p][4+j] = (bf16)a[2*p+1][j];
        }
      bf16* dst = Xbf + (size_t)row*KP_ + s0;
#pragma unroll
      for (int p = 0; p < 4; ++p) *(bf16x8*)(dst + 8*p) = o[p];
    }
  } else if (blk < 3584) {
    // wmix_t (R24-proven): 1536 blocks = 64 b x 24 d-chunks(32)
    __shared__ float tile[32][33];
    const int wb = blk - 2048;
    const int b  = wb / 24;
    const int dc = wb - b*24;
    const int d0 = dc << 5;
    const float* logits; const unsigned* masks = pick_masks(cA, cB, &logits);
    const Gate g = gate_for(logits, masks, b);
    const float* W1 = W + (size_t)g.e1*FD_;
    const float* W2 = W + (size_t)g.e2*FD_;
    const int t = threadIdx.x;
    const int c = t & 31, r = t >> 5;
    const int dl = t >> 3, qd = t & 7;
    bf16* dstb = Wmix + ((size_t)b*D_ + d0 + dl)*KP_;
#pragma unroll 1
    for (int ft = 0; ft < 29; ++ft) {
      const int f0 = ft << 5;
      float v[4];
#pragma unroll
      for (int p = 0; p < 4; ++p) {
        const int f = f0 + (p << 3) + r;
        if (f < F_) {
          const size_t o = (size_t)f*D_ + d0 + c;
          v[p] = g.p1*W1[o] + g.p2*W2[o];
        } else v[p] = 0.f;
      }
      __syncthreads();
#pragma unroll
      for (int p = 0; p < 4; ++p) tile[(p << 3) + r][c] = v[p];
      __syncthreads();
      bf16x4 pk;
#pragma unroll
      for (int j = 0; j < 4; ++j) pk[j] = (bf16)tile[(qd << 2) + j][dl];
      *(bf16x4*)(dstb + f0 + (qd << 2)) = pk;
    }
  } else {
    if (threadIdx.x < 64) gating_body(cA, cB, selemb, fout, threadIdx.x);
  }
}

// ---- gemm v3 (R23/R24 verbatim, replay-proven): 3-deep, vmcnt exact --------
__global__ __launch_bounds__(256) void gemm_fast(
    const bf16* __restrict__ Xbf, const bf16* __restrict__ Wmix,
    const float* __restrict__ bias,
    const void* cA, const void* cB,
    float* __restrict__ fout) {
  __shared__ bf16 As[3][128*32];
  __shared__ bf16 Bs[3][128*32];

  const int id  = blockIdx.x;
  const int xcd = id & 7, q = id >> 3;        // 3072 = 8 * 384
  const int b   = xcd + ((q / 48) << 3);      // 48 consecutive q = one batch
  const int j   = q % 48;
  const int bn  = j % 6, bm = j / 6;

  const float* logits; const unsigned* masks = pick_masks(cA, cB, &logits);
  const Gate g = gate_for(logits, masks, b);

  const bf16* Ab = Xbf  + ((size_t)b*L_ + (size_t)bm*128) * KP_;
  const bf16* Bb = Wmix + ((size_t)b*D_ + (size_t)bn*128) * KP_;

  const int t = threadIdx.x, lane = t & 63, w = t >> 6;
  const int sw   = ((lane & 3) ^ ((lane >> 2) & 3)) << 3;   // pre-swizzle
  const int row0 = (w << 5) + (lane >> 2);
  const int row1 = row0 + 16;
  const int dst0 = (w << 7) << 3;
  const int dst1 = dst0 + (64 << 3);

  auto STAGE = [&](int buf, int kt) {
    const int k0 = kt << 5;
    gload16(Ab + (size_t)row0*KP_ + k0 + sw, &As[buf][dst0]);
    gload16(Ab + (size_t)row1*KP_ + k0 + sw, &As[buf][dst1]);
    gload16(Bb + (size_t)row0*KP_ + k0 + sw, &Bs[buf][dst0]);
    gload16(Bb + (size_t)row1*KP_ + k0 + sw, &Bs[buf][dst1]);
  };

  const int wr = (w >> 1) << 6, wc = (w & 1) << 6;   // 64x64 wave tile
  const int fr = lane & 15, fks = lane >> 4;
  const int rq = (lane >> 4) << 2;

  int aoff[4], boff[4];
#pragma unroll
  for (int m = 0; m < 4; ++m) {
    int rA = wr + m*16 + fr;
    aoff[m] = rA*32 + ((fks ^ (rA & 3)) << 3);
    int rB = wc + m*16 + fr;
    boff[m] = rB*32 + ((fks ^ (rB & 3)) << 3);
  }

  // bias preload (keeps in-loop VMEM = exactly 4 gload16/iter)
  const float* b1 = bias + g.e1*D_;
  const float* b2 = bias + g.e2*D_;
  float bsv[4];
#pragma unroll
  for (int n = 0; n < 4; ++n) {
    int gc = bn*128 + wc + n*16 + fr;
    bsv[n] = g.p1*b1[gc] + g.p2*b2[gc];
  }

  f32x4 acc[4][4];
#pragma unroll
  for (int m = 0; m < 4; ++m)
#pragma unroll
    for (int n = 0; n < 4; ++n) acc[m][n] = (f32x4){0.f,0.f,0.f,0.f};

  STAGE(0, 0);
  STAGE(1, 1);
  int cur = 0;
#pragma unroll 1
  for (int kt = 0; kt < NT_; ++kt) {
    if (kt + 2 < NT_) {
      const int sb = (cur + 2 >= 3) ? cur - 1 : cur + 2;
      STAGE(sb, kt + 2);               // 12 outstanding after issue
      asm volatile("s_waitcnt vmcnt(8)" ::: "memory");   // tile kt landed
    } else if (kt + 2 == NT_) {
      asm volatile("s_waitcnt vmcnt(4)" ::: "memory");
    } else {
      asm volatile("s_waitcnt vmcnt(0)" ::: "memory");
    }
    __builtin_amdgcn_sched_barrier(0);
    __builtin_amdgcn_s_barrier();
    __builtin_amdgcn_sched_barrier(0);
    bf16x8 af[4], bfv[4];
#pragma unroll
    for (int m = 0; m < 4; ++m) af[m]  = *(const bf16x8*)&As[cur][aoff[m]];
#pragma unroll
    for (int n = 0; n < 4; ++n) bfv[n] = *(const bf16x8*)&Bs[cur][boff[n]];
#pragma unroll
    for (int m = 0; m < 4; ++m)
#pragma unroll
      for (int n = 0; n < 4; ++n)
        acc[m][n] = mfma_bf16(af[m], bfv[n], acc[m][n]);
    __builtin_amdgcn_sched_barrier(0);
    __builtin_amdgcn_s_barrier();      // WAR guard
    cur = (cur + 1 == 3) ? 0 : cur + 1;
  }

  // epilogue (f32): C/D layout col=lane&15, row=(lane>>4)*4+i (R17-verified)
#pragma unroll
  for (int n = 0; n < 4; ++n) {
    int gc = bn*128 + wc + n*16 + fr;
#pragma unroll
    for (int m = 0; m < 4; ++m) {
      size_t base = ((size_t)b*L_ + (size_t)(bm*128 + wr + m*16 + rq)) * D_ + gc;
#pragma unroll
      for (int i = 0; i < 4; ++i)
        fout[base + (size_t)i*D_] = acc[m][n][i] + bsv[n];
    }
  }
}

// ======================= R17 mid path (ws >= 11.4MB) ========================
__global__ void transw_kernel(const float* __restrict__ W, bf16* __restrict__ Wt) {
  __shared__ float tile[32][33];
  const int e  = blockIdx.z;
  const int d0 = blockIdx.x << 5;
  const int f0 = blockIdx.y << 5;
  const int c = threadIdx.x & 31, r = threadIdx.x >> 5;
#pragma unroll
  for (int p = 0; p < 4; ++p) {
    int f = f0 + p*8 + r;
    tile[p*8+r][c] = (f < F_) ? W[((size_t)e*F_ + f)*D_ + d0 + c] : 0.f;
  }
  __syncthreads();
#pragma unroll
  for (int p = 0; p < 4; ++p) {
    int d = d0 + p*8 + r;
    Wt[((size_t)e*D_ + d)*KP_ + f0 + c] = (bf16)tile[c][p*8+r];
  }
}

__global__ __launch_bounds__(256) void gemm_kernel(
    const float* __restrict__ X, const bf16* __restrict__ Wt,
    const float* __restrict__ bias,
    const void* cA, const void* cB,
    float* __restrict__ fout) {
  __shared__ bf16 As[128][40];
  __shared__ bf16 Bs[128][40];
  const int bn = blockIdx.x, bm = blockIdx.y, b = blockIdx.z;
  const float* logits; const unsigned* masks = pick_masks(cA, cB, &logits);
  const Gate g = gate_for(logits, masks, b);
  const float* Xb = X + ((size_t)b*L_ + (size_t)bm*128) * F_;
  const bf16* W1 = Wt + ((size_t)g.e1*D_ + (size_t)bn*128) * KP_;
  const bf16* W2 = Wt + ((size_t)g.e2*D_ + (size_t)bn*128) * KP_;
  const int t  = threadIdx.x;
  const int ar = t >> 3, ac = (t & 7) << 2;
  const int br = t >> 2, bc = (t & 3) << 3;
  const int lane = t & 63, wave = t >> 6;
  const int wr = (wave >> 1) << 6, wc = (wave & 1) << 6;
  const int fr = lane & 15, fk = (lane >> 4) << 3;
  const int rq = (lane >> 4) << 2;
  f32x4 acc[4][4];
#pragma unroll
  for (int m = 0; m < 4; ++m)
#pragma unroll
    for (int n = 0; n < 4; ++n) acc[m][n] = (f32x4){0.f,0.f,0.f,0.f};
  f32x4 ax[4]; bf16x8 wv1[2], wv2[2];
  auto LOAD = [&](int k0) {
    if (k0 <= F_ - 32) {
#pragma unroll
      for (int p = 0; p < 4; ++p)
        ax[p] = *(const f32x4*)(Xb + (size_t)(p*32 + ar)*F_ + k0 + ac);
    } else {
#pragma unroll
      for (int p = 0; p < 4; ++p)
#pragma unroll
        for (int jj = 0; jj < 4; ++jj) {
          int k = k0 + ac + jj;
          ax[p][jj] = (k < F_) ? Xb[(size_t)(p*32 + ar)*F_ + k] : 0.f;
        }
    }
#pragma unroll
    for (int p = 0; p < 2; ++p) {
      wv1[p] = *(const bf16x8*)(W1 + (size_t)(p*64 + br)*KP_ + k0 + bc);
      wv2[p] = *(const bf16x8*)(W2 + (size_t)(p*64 + br)*KP_ + k0 + bc);
    }
  };
  auto STAGE = [&]() {
#pragma unroll
    for (int p = 0; p < 4; ++p) {
      bf16x4 v;
#pragma unroll
      for (int jj = 0; jj < 4; ++jj) v[jj] = (bf16)ax[p][jj];
      *(bf16x4*)&As[p*32 + ar][ac] = v;
    }
#pragma unroll
    for (int p = 0; p < 2; ++p) {
      bf16x8 v;
#pragma unroll
      for (int jj = 0; jj < 8; ++jj)
        v[jj] = (bf16)(g.p1 * (float)wv1[p][jj] + g.p2 * (float)wv2[p][jj]);
      *(bf16x8*)&Bs[p*64 + br][bc] = v;
    }
  };
  LOAD(0);
  for (int kt = 0; kt < NT_; ++kt) {
    STAGE();
    __syncthreads();
    if (kt + 1 < NT_) LOAD((kt + 1) << 5);
    bf16x8 af[4], bfv[4];
#pragma unroll
    for (int m = 0; m < 4; ++m) af[m]  = *(const bf16x8*)&As[wr + m*16 + fr][fk];
#pragma unroll
    for (int n = 0; n < 4; ++n) bfv[n] = *(const bf16x8*)&Bs[wc + n*16 + fr][fk];
#pragma unroll
    for (int m = 0; m < 4; ++m)
#pragma unroll
      for (int n = 0; n < 4; ++n)
        acc[m][n] = mfma_bf16(af[m], bfv[n], acc[m][n]);
    __syncthreads();
  }
  const float* b1 = bias + g.e1*D_;
  const float* b2 = bias + g.e2*D_;
#pragma unroll
  for (int n = 0; n < 4; ++n) {
    int gc = bn*128 + wc + n*16 + fr;
    float bs = g.p1*b1[gc] + g.p2*b2[gc];
#pragma unroll
    for (int m = 0; m < 4; ++m) {
      size_t base = ((size_t)b*L_ + (size_t)(bm*128 + wr + m*16 + rq)) * D_ + gc;
#pragma unroll
      for (int i = 0; i < 4; ++i)
        fout[base + (size_t)i*D_] = acc[m][n][i] + bs;
    }
  }
}

// ---- last-resort f32 fallback (ws too small) -------------------------------
__global__ __launch_bounds__(128) void fallback_kernel(
    const float* __restrict__ X, const float* __restrict__ W,
    const float* __restrict__ bias,
    const void* cA, const void* cB,
    float* __restrict__ fout) {
  __shared__ float xs[16 * F_];
  const int t  = threadIdx.x;
  const int d  = blockIdx.x * 128 + t;
  const int l0 = blockIdx.y * 16;
  const int b  = blockIdx.z;
  const float* logits; const unsigned* masks = pick_masks(cA, cB, &logits);
  const Gate g = gate_for(logits, masks, b);
  const float* xrow = X + ((size_t)b*L_ + l0) * F_;
  for (int i = t; i < 16 * F_; i += 128) xs[i] = xrow[i];
  __syncthreads();
  const float* w1 = W + (size_t)g.e1*FD_ + d;
  const float* w2 = W + (size_t)g.e2*FD_ + d;
  float acc[16];
#pragma unroll
  for (int jj = 0; jj < 16; ++jj) acc[jj] = 0.f;
  for (int k = 0; k < F_; k += 4) {
    float wb[4];
#pragma unroll
    for (int qq = 0; qq < 4; ++qq)
      wb[qq] = g.p1 * w1[(size_t)(k+qq)*D_] + g.p2 * w2[(size_t)(k+qq)*D_];
#pragma unroll
    for (int jj = 0; jj < 16; ++jj) {
      f32x4 xv = *(const f32x4*)&xs[jj*F_ + k];
#pragma unroll
      for (int qq = 0; qq < 4; ++qq) acc[jj] += xv[qq] * wb[qq];
    }
  }
  const float bs = g.p1*bias[g.e1*D_+d] + g.p2*bias[g.e2*D_+d];
#pragma unroll
  for (int jj = 0; jj < 16; ++jj)
    fout[((size_t)b*L_ + (size_t)(l0 + jj)) * D_ + d] = acc[jj] + bs;
}

extern "C" void kernel_launch(void* const* d_in, const int* in_sizes, int n_in,
                              void* d_out, int out_size, void* d_ws, size_t ws_size,
                              hipStream_t stream) {
  const float *X = nullptr, *selemb = nullptr, *W = nullptr, *bias = nullptr;
  const void *cA = nullptr, *cB = nullptr;
  for (int i = 0; i < n_in; ++i) {
    switch (in_sizes[i]) {
      case 58982400: X      = (const float*)d_in[i]; break;
      case 32768:    selemb = (const float*)d_in[i]; break;
      case 5529600:  W      = (const float*)d_in[i]; break;
      case 6144:     bias   = (const float*)d_in[i]; break;
      case 512:      if (!cA) cA = d_in[i]; else cB = d_in[i]; break;
      default: break;
    }
  }
  if (!X)      X      = (const float*)d_in[0];
  if (!cA)     cA     = d_in[1];
  if (!cB)     cB     = d_in[2];
  if (!selemb) selemb = (const float*)d_in[3];
  if (!W)      W      = (const float*)d_in[4];
  if (!bias)   bias   = (const float*)d_in[5];
  float* fout = (float*)d_out;

  const size_t xbf_bytes  = (size_t)B_*L_*KP_*2;         // 121,634,816
  const size_t wmix_bytes = (size_t)B_*D_*KP_*2;         //  91,226,112
  const size_t need_fast  = xbf_bytes + wmix_bytes;      // ~203 MB
  const size_t need_mid   = (size_t)E_*D_*KP_*2;         // ~11.4 MB

  if (ws_size >= need_fast) {
    bf16* Xbf  = (bf16*)d_ws;
    bf16* Wmix = (bf16*)((char*)d_ws + xbf_bytes);
    prep_kernel<<<3585, 256, 0, stream>>>(X, W, cA, cB, selemb, Xbf, Wmix, fout);
    gemm_fast<<<3072, 256, 0, stream>>>(Xbf, Wmix, bias, cA, cB, fout);
  } else if (ws_size >= need_mid) {
    bf16* Wt = (bf16*)d_ws;
    gating_kernel<<<1, 64, 0, stream>>>(cA, cB, selemb, fout);
    transw_kernel<<<dim3(24, 29, 8), 256, 0, stream>>>(W, Wt);
    gemm_kernel<<<dim3(6, 8, 64), 256, 0, stream>>>(X, Wt, bias, cA, cB, fout);
  } else {
    gating_kernel<<<1, 64, 0, stream>>>(cA, cB, selemb, fout);
    fallback_kernel<<<dim3(6, 64, 64), 128, 0, stream>>>(X, W, bias, cA, cB, fout);
  }
}